// Round 2
// baseline (1659.118 us; speedup 1.0000x reference)
//
#include <hip/hip_runtime.h>
#include <hip/hip_bf16.h>
#include <math.h>

static constexpr int BN_ = 2;
static constexpr int CA = 256, HA = 64, WA = 128;   // stage A input
static constexpr int OO = 128;                      // output channels (both stages)
static constexpr int HC = 128, WC = 256, CC = 128;  // stage C spatial / channels

// ---------------- weight transpose: w[O][C][9] -> wk[9][C][O] ----------------
__global__ void wk_transpose_kernel(const float* __restrict__ w,
                                    float* __restrict__ wk, int Cin) {
    int idx = blockIdx.x * blockDim.x + threadIdx.x;
    int total = OO * Cin * 9;
    if (idx >= total) return;
    int o = idx % OO;
    int c = (idx / OO) % Cin;
    int k = idx / (OO * Cin);
    wk[idx] = w[((size_t)o * Cin + c) * 9 + k];
}

// ---------------- 3x3 conv producing the 27-channel offset/mask map ----------
template<int C, int H, int W>
__global__ __launch_bounds__(256) void om_conv_kernel(
    const float* __restrict__ x,    // [B][C][H][W]
    const float* __restrict__ wom,  // [27][C][3][3]
    const float* __restrict__ bom,  // [27]
    float* __restrict__ om)         // [B][27][H][W]
{
    constexpr int CSUB = C / 4;
    const int nwt = W / 64;
    int wt = blockIdx.x % nwt;
    int h  = (blockIdx.x / nwt) % H;
    int b  = blockIdx.x / (nwt * H);
    int t = threadIdx.x;
    int pos = t & 63;
    int sub = t >> 6;            // wave-aligned channel subset -> uniform weight loads
    int w = wt * 64 + pos;

    float acc[27];
#pragma unroll
    for (int i = 0; i < 27; i++) acc[i] = 0.f;

    int wm = max(w - 1, 0), wp = min(w + 1, W - 1);
    bool wmv = (w - 1) >= 0, wpv = (w + 1) < W;

    const float* xb = x + (size_t)b * C * H * W;
    for (int ci = 0; ci < CSUB; ci++) {
        int c = sub * CSUB + ci;
        const float* cp = xb + (size_t)c * H * W;
        float v[9];
#pragma unroll
        for (int dy = 0; dy < 3; dy++) {
            int hh = h + dy - 1;
            bool rv = (hh >= 0) && (hh < H);
            int hcl = min(max(hh, 0), H - 1);
            const float* rp = cp + (size_t)hcl * W;
            float a0 = rp[wm], a1 = rp[w], a2 = rp[wp];
            v[dy * 3 + 0] = (rv && wmv) ? a0 : 0.f;
            v[dy * 3 + 1] = rv ? a1 : 0.f;
            v[dy * 3 + 2] = (rv && wpv) ? a2 : 0.f;
        }
#pragma unroll 1
        for (int oc = 0; oc < 27; oc++) {
            const float* wr = wom + ((size_t)oc * C + c) * 9;
            float s = v[0] * wr[0];
            s = fmaf(v[1], wr[1], s);
            s = fmaf(v[2], wr[2], s);
            s = fmaf(v[3], wr[3], s);
            s = fmaf(v[4], wr[4], s);
            s = fmaf(v[5], wr[5], s);
            s = fmaf(v[6], wr[6], s);
            s = fmaf(v[7], wr[7], s);
            s = fmaf(v[8], wr[8], s);
            acc[oc] += s;
        }
    }

    __shared__ float red[4][64][28];
#pragma unroll
    for (int oc = 0; oc < 27; oc++) red[sub][pos][oc] = acc[oc];
    __syncthreads();
    for (int idx = t; idx < 27 * 64; idx += 256) {
        int oc = idx >> 6;
        int p  = idx & 63;
        float s = red[0][p][oc] + red[1][p][oc] + red[2][p][oc] + red[3][p][oc] + bom[oc];
        om[(((size_t)b * 27 + oc) * H + h) * W + wt * 64 + p] = s;
    }
}

// ---------------- DCN main: sample + einsum + bias + BN + ReLU ---------------
template<int C, int H, int W>
__global__ __launch_bounds__(256) void dcn_main_kernel(
    const float* __restrict__ x,    // [B][C][H][W]
    const float* __restrict__ om,   // [B][27][H][W]
    const float* __restrict__ wk,   // [9][C][O]
    const float* __restrict__ bias,
    const float* __restrict__ gamma, const float* __restrict__ beta,
    const float* __restrict__ mean,  const float* __restrict__ var,
    float* __restrict__ outf)       // [B][O][H][W]  (fp32)
{
    constexpr int CS = 32;
    constexpr int NCH = C / CS;
    const int nwt = W / 64;
    int wt = blockIdx.x % nwt;
    int h  = (blockIdx.x / nwt) % H;
    int b  = blockIdx.x / (nwt * H);
    int t = threadIdx.x;

    __shared__ int   pki[576][5];   // y0*W, y1*W, x0, x1 (clamped); pad->2-way banks
    __shared__ float pkw[576][5];   // 4 corner weights with validity & sigmoid(m) folded
    __shared__ float slds[CS][68];  // s[c][pos], row pad 4 -> 16B-aligned b128 reads

    // ---- per-(pos,k) precompute ----
    const float* omb = om + ((size_t)b * 27) * H * W + (size_t)h * W + wt * 64;
    for (int idx = t; idx < 576; idx += 256) {
        int p = idx & 63;
        int k = idx >> 6;
        float o1 = omb[(size_t)k * H * W + p];
        float o2 = omb[(size_t)(9 + k) * H * W + p];
        float mm = omb[(size_t)(18 + k) * H * W + p];
        mm = 1.f / (1.f + expf(-mm));
        float py = o1 + (float)(h + k / 3 - 1);
        float px = o2 + (float)(wt * 64 + p + (k % 3) - 1);
        float y0f = floorf(py), x0f = floorf(px);
        float wy = py - y0f, wx = px - x0f;
        int y0 = (int)y0f, x0 = (int)x0f;
        bool y0v = (y0 >= 0) && (y0 < H);
        bool y1v = (y0 + 1 >= 0) && (y0 + 1 < H);
        bool x0v = (x0 >= 0) && (x0 < W);
        bool x1v = (x0 + 1 >= 0) && (x0 + 1 < W);
        pki[idx][0] = min(max(y0, 0), H - 1) * W;
        pki[idx][1] = min(max(y0 + 1, 0), H - 1) * W;
        pki[idx][2] = min(max(x0, 0), W - 1);
        pki[idx][3] = min(max(x0 + 1, 0), W - 1);
        pkw[idx][0] = (y0v && x0v) ? (1.f - wy) * (1.f - wx) * mm : 0.f;
        pkw[idx][1] = (y0v && x1v) ? (1.f - wy) * wx * mm : 0.f;
        pkw[idx][2] = (y1v && x0v) ? wy * (1.f - wx) * mm : 0.f;
        pkw[idx][3] = (y1v && x1v) ? wy * wx * mm : 0.f;
    }
    __syncthreads();

    int og = t & 31;   // o = og*4 .. +3
    int pg = t >> 5;   // pos = pg*8 .. +7
    float acc[8][4];
#pragma unroll
    for (int p = 0; p < 8; p++)
#pragma unroll
        for (int j = 0; j < 4; j++) acc[p][j] = 0.f;

    const float* xb = x + (size_t)b * C * H * W;
    int ci = t >> 3;   // phase-1 channel within chunk
    int po = t & 7;    // phase-1 pos octet

    for (int k = 0; k < 9; k++) {
        const int*   pib = &pki[k * 64][0];
        const float* pwb = &pkw[k * 64][0];
        for (int ch = 0; ch < NCH; ch++) {
            // phase 1: gather s[c][pos] for this (k, chunk)
            {
                int c = ch * CS + ci;
                const float* cp = xb + (size_t)c * H * W;
#pragma unroll
                for (int i = 0; i < 8; i++) {
                    int p = po * 8 + i;
                    int yw0 = pib[p * 5 + 0], yw1 = pib[p * 5 + 1];
                    int xx0 = pib[p * 5 + 2], xx1 = pib[p * 5 + 3];
                    float w00 = pwb[p * 5 + 0], w01 = pwb[p * 5 + 1];
                    float w10 = pwb[p * 5 + 2], w11 = pwb[p * 5 + 3];
                    float v = w00 * cp[yw0 + xx0];
                    v = fmaf(w01, cp[yw0 + xx1], v);
                    v = fmaf(w10, cp[yw1 + xx0], v);
                    v = fmaf(w11, cp[yw1 + xx1], v);
                    slds[ci][p] = v;
                }
            }
            __syncthreads();
            // phase 2: acc[pos][o] += s[pos][c] * wk[k][c][o]
            const float* wkp = wk + ((size_t)k * C + ch * CS) * OO + og * 4;
#pragma unroll 4
            for (int cc = 0; cc < CS; cc++) {
                float4 wv = *reinterpret_cast<const float4*>(wkp + (size_t)cc * OO);
                const float* sp = &slds[cc][pg * 8];
#pragma unroll
                for (int p = 0; p < 8; p++) {
                    float sv = sp[p];
                    acc[p][0] = fmaf(sv, wv.x, acc[p][0]);
                    acc[p][1] = fmaf(sv, wv.y, acc[p][1]);
                    acc[p][2] = fmaf(sv, wv.z, acc[p][2]);
                    acc[p][3] = fmaf(sv, wv.w, acc[p][3]);
                }
            }
            __syncthreads();
        }
    }

    // epilogue: bias + BN + ReLU, store fp32
#pragma unroll
    for (int j = 0; j < 4; j++) {
        int o = og * 4 + j;
        float inv = gamma[o] * rsqrtf(var[o] + 1e-5f);
        float mu = mean[o], bt = beta[o], bb = bias[o];
        size_t base = (((size_t)b * OO + o) * H + h) * W + (size_t)wt * 64 + pg * 8;
#pragma unroll
        for (int p = 0; p < 8; p++) {
            float y = acc[p][j] + bb;
            y = (y - mu) * inv + bt;
            y = fmaxf(y, 0.f);
            outf[base + p] = y;
        }
    }
}

// ---------------- bilinear x2 depthwise transposed conv + residual ----------
__global__ __launch_bounds__(256) void upsample_add_kernel(
    const float* __restrict__ h1,   // [B][O][HA][WA]
    const float* __restrict__ prex, // [B][O][HC][WC]
    const float* __restrict__ upw,  // [O][1][4][4]
    float* __restrict__ z)          // [B][O][HC][WC]
{
    int idx = blockIdx.x * blockDim.x + threadIdx.x;
    constexpr int total = BN_ * OO * HC * WC;
    if (idx >= total) return;
    int X = idx & (WC - 1);
    int Y = (idx / WC) & (HC - 1);
    int c = (idx / (WC * HC)) % OO;
    int bc = idx / (WC * HC);   // b*O + c

    int sy0, iy0, sy1, iy1, sx0, ix0, sx1, ix1;
    if (Y & 1) { sy0 = (Y - 1) >> 1; iy0 = 2; sy1 = sy0 + 1; iy1 = 0; }
    else       { sy0 = (Y >> 1) - 1; iy0 = 3; sy1 = sy0 + 1; iy1 = 1; }
    if (X & 1) { sx0 = (X - 1) >> 1; ix0 = 2; sx1 = sx0 + 1; ix1 = 0; }
    else       { sx0 = (X >> 1) - 1; ix0 = 3; sx1 = sx0 + 1; ix1 = 1; }

    const float* wp = upw + (size_t)c * 16;
    const float* hp = h1 + (size_t)bc * HA * WA;
    bool y0v = sy0 >= 0, y1v = sy1 < HA;
    bool x0v = sx0 >= 0, x1v = sx1 < WA;

    float acc = prex[idx];
    if (y0v) {
        const float* r = hp + (size_t)sy0 * WA;
        if (x0v) acc = fmaf(r[sx0], wp[iy0 * 4 + ix0], acc);
        if (x1v) acc = fmaf(r[sx1], wp[iy0 * 4 + ix1], acc);
    }
    if (y1v) {
        const float* r = hp + (size_t)sy1 * WA;
        if (x0v) acc = fmaf(r[sx0], wp[iy1 * 4 + ix0], acc);
        if (x1v) acc = fmaf(r[sx1], wp[iy1 * 4 + ix1], acc);
    }
    z[idx] = acc;
}

// ---------------- launch ----------------
extern "C" void kernel_launch(void* const* d_in, const int* in_sizes, int n_in,
                              void* d_out, int out_size, void* d_ws, size_t ws_size,
                              hipStream_t stream) {
    (void)in_sizes; (void)n_in; (void)out_size; (void)ws_size;
    const float* x      = (const float*)d_in[0];
    const float* pre_x  = (const float*)d_in[1];
    const float* pwom   = (const float*)d_in[2];
    const float* pbom   = (const float*)d_in[3];
    const float* pw     = (const float*)d_in[4];
    const float* pb     = (const float*)d_in[5];
    const float* pgam   = (const float*)d_in[6];
    const float* pbet   = (const float*)d_in[7];
    const float* pmea   = (const float*)d_in[8];
    const float* pvar   = (const float*)d_in[9];
    const float* nwom   = (const float*)d_in[10];
    const float* nbom   = (const float*)d_in[11];
    const float* nw     = (const float*)d_in[12];
    const float* nb     = (const float*)d_in[13];
    const float* ngam   = (const float*)d_in[14];
    const float* nbet   = (const float*)d_in[15];
    const float* nmea   = (const float*)d_in[16];
    const float* nvar   = (const float*)d_in[17];
    const float* upw    = (const float*)d_in[18];
    float* out = (float*)d_out;     // reference output dtype is float32

    // workspace layout (floats); omC aliases the dead h1+omA region
    float* ws  = (float*)d_ws;
    float* z   = ws;                 // 8,388,608  (2,128,128,256)
    float* h1  = z   + 8388608;      // 2,097,152  (2,128,64,128)
    float* omA = h1  + 2097152;      //   442,368  (2,27,64,128)
    float* omC = h1;                 // 1,769,472  (2,27,128,256) - reuses h1+omA
    float* wkA = omA + 442368;       //   294,912  (9,256,128)
    float* wkC = wkA + 294912;       //   147,456  (9,128,128)
    // total: 11,370,496 floats = 45.5 MB

    wk_transpose_kernel<<<(294912 + 255) / 256, 256, 0, stream>>>(pw, wkA, CA);
    wk_transpose_kernel<<<(147456 + 255) / 256, 256, 0, stream>>>(nw, wkC, CC);

    om_conv_kernel<CA, HA, WA><<<BN_ * HA * (WA / 64), 256, 0, stream>>>(x, pwom, pbom, omA);
    dcn_main_kernel<CA, HA, WA><<<BN_ * HA * (WA / 64), 256, 0, stream>>>(
        x, omA, wkA, pb, pgam, pbet, pmea, pvar, h1);

    upsample_add_kernel<<<(BN_ * OO * HC * WC + 255) / 256, 256, 0, stream>>>(h1, pre_x, upw, z);

    om_conv_kernel<CC, HC, WC><<<BN_ * HC * (WC / 64), 256, 0, stream>>>(z, nwom, nbom, omC);
    dcn_main_kernel<CC, HC, WC><<<BN_ * HC * (WC / 64), 256, 0, stream>>>(
        z, omC, wkC, nb, ngam, nbet, nmea, nvar, out);
}

// Round 5
// 1154.150 us; speedup vs baseline: 1.4375x; 1.4375x over previous
//
#include <hip/hip_runtime.h>
#include <hip/hip_bf16.h>
#include <math.h>

typedef __bf16 bf16x8 __attribute__((ext_vector_type(8)));
typedef float  f32x4  __attribute__((ext_vector_type(4)));

static constexpr int BN2 = 2;
static constexpr int CA = 256, HA = 64, WA = 128;   // stage A input
static constexpr int OO = 128;                      // output channels
static constexpr int HC = 128, WC = 256, CC = 128;  // stage C

// ---------- fp32 weight transpose: w[O][C][9] -> wkt[9][C][O] (R2-proven) ----------
__global__ void wk_transpose_kernel(const float* __restrict__ w,
                                    float* __restrict__ wk, int Cin) {
    int idx = blockIdx.x * blockDim.x + threadIdx.x;
    int total = OO * Cin * 9;
    if (idx >= total) return;
    int o = idx % OO;
    int c = (idx / OO) % Cin;
    int k = idx / (OO * Cin);
    wk[idx] = w[((size_t)o * Cin + c) * 9 + k];
}

// ---------- pack om weights fp32: womt[9][C/8][28][8] ----------
__global__ void pack_womt_kernel(const float* __restrict__ w, float* __restrict__ out, int Cin) {
    int C8 = Cin / 8;
    int idx = blockIdx.x * blockDim.x + threadIdx.x;
    int total = 9 * C8 * 28 * 8;
    if (idx >= total) return;
    int j  = idx & 7;
    int oc = (idx >> 3) % 28;
    int c8 = (idx / (8 * 28)) % C8;
    int k  = idx / (8 * 28 * C8);
    float v = (oc < 27) ? w[((size_t)oc * Cin + (c8 * 8 + j)) * 9 + k] : 0.f;
    out[idx] = v;
}

// ---------- NCHW fp32 -> NHWC bf16 (LDS tile transpose) ----------
template<int C, int HW>
__global__ __launch_bounds__(256) void to_cl_kernel(const float* __restrict__ x,
                                                    __bf16* __restrict__ xcl) {
    constexpr int NCB = C / 32;
    constexpr int NPB = HW / 64;
    int blk = blockIdx.x;
    int pblk = blk % NPB;
    int cblk = (blk / NPB) % NCB;
    int b = blk / (NPB * NCB);
    int t = threadIdx.x;
    __shared__ float st[32][65];
    int r = t >> 6, q = t & 63;
#pragma unroll
    for (int i = 0; i < 8; i++) {
        int c = cblk * 32 + i * 4 + r;
        st[i * 4 + r][q] = x[((size_t)b * C + c) * HW + pblk * 64 + q];
    }
    __syncthreads();
    int p = t >> 2, cq = t & 3;
    bf16x8 v;
#pragma unroll
    for (int j = 0; j < 8; j++) v[j] = (__bf16)st[cq * 8 + j][p];
    *reinterpret_cast<bf16x8*>(xcl + ((size_t)b * HW + pblk * 64 + p) * C + cblk * 32 + cq * 8) = v;
}

// ---------- fold bias+BN into per-o scale/shift ----------
__global__ void bn_prepack_kernel(const float* __restrict__ g,  const float* __restrict__ be,
                                  const float* __restrict__ mu, const float* __restrict__ va,
                                  const float* __restrict__ bi,
                                  float* __restrict__ sc, float* __restrict__ sh) {
    int i = blockIdx.x * blockDim.x + threadIdx.x;
    if (i >= OO) return;
    float s = g[i] * rsqrtf(va[i] + 1e-5f);
    sc[i] = s;
    sh[i] = (bi[i] - mu[i]) * s + be[i];
}

// ---------- upw[O][4][4] -> upwt[16][O] ----------
__global__ void pack_upw_kernel(const float* __restrict__ upw, float* __restrict__ upwt) {
    int idx = blockIdx.x * blockDim.x + threadIdx.x;
    if (idx >= 16 * OO) return;
    int i = idx >> 7;
    int o = idx & 127;
    upwt[i * OO + o] = upw[o * 16 + i];
}

// ---------- scalar om-conv: channel-last in, channel-last om out ----------
template<int C, int H, int W>
__global__ __launch_bounds__(256) void om_conv_scalar_kernel(
    const __bf16* __restrict__ xcl,   // [B][H][W][C]
    const float* __restrict__ womt,   // [9][C/8][28][8] fp32
    const float* __restrict__ bom,    // [27]
    float* __restrict__ omcl)         // [B][H][W][32]
{
    constexpr int C8 = C / 8;
    const int nwt = W / 64;
    int wt = blockIdx.x % nwt;
    int h  = (blockIdx.x / nwt) % H;
    int b  = blockIdx.x / (nwt * H);
    int t = threadIdx.x;
    int pc = t & 63;
    int grp = t >> 6;
    int oc0 = grp * 7;
    int noc = (grp < 3) ? 7 : 6;
    int w = wt * 64 + pc;

    float acc[7];
#pragma unroll
    for (int i = 0; i < 7; i++) acc[i] = 0.f;

    const __bf16* xb = xcl + (size_t)b * H * W * C;
    for (int k = 0; k < 9; k++) {
        int y = h + k / 3 - 1, xx = w + k % 3 - 1;
        bool valid = (y >= 0) && (y < H) && (xx >= 0) && (xx < W);
        if (!valid) continue;
        const __bf16* px = xb + ((size_t)y * W + xx) * C;
        const float* wkb = womt + (size_t)k * C8 * 28 * 8;
        for (int c8 = 0; c8 < C8; c8++) {
            bf16x8 xv = *reinterpret_cast<const bf16x8*>(px + c8 * 8);
            float xf[8];
#pragma unroll
            for (int j = 0; j < 8; j++) xf[j] = (float)xv[j];
            const float* wrow = wkb + ((size_t)c8 * 28 + oc0) * 8;
#pragma unroll
            for (int i = 0; i < 7; i++) {
                if (i < noc) {
#pragma unroll
                    for (int j = 0; j < 8; j++)
                        acc[i] = fmaf(xf[j], wrow[i * 8 + j], acc[i]);
                }
            }
        }
    }
    float* ob = omcl + (((size_t)b * H + h) * W + w) * 32;
    for (int i = 0; i < noc; i++) ob[oc0 + i] = acc[i] + bom[oc0 + i];
}

// ---------- BISECT: scalar DCN on channel-last bf16 (R2-proven structure) ----------
template<int C, int H, int W, bool CF_OUT>
__global__ __launch_bounds__(256) void dcn_scalar_cl_kernel(
    const __bf16* __restrict__ xcl,  // [B][H][W][C]
    const float* __restrict__ omcl,  // [B][H][W][32]
    const float* __restrict__ wkt,   // [9][C][O] fp32
    const float* __restrict__ sc, const float* __restrict__ sh,
    float* __restrict__ outcf,       // CF_OUT: [B][O][H][W] fp32
    __bf16* __restrict__ outcl)      // else:   [B][H][W][O] bf16
{
    constexpr int NCH = C / 32;
    const int nwt = W / 64;
    int wt = blockIdx.x % nwt;
    int h  = (blockIdx.x / nwt) % H;
    int b  = blockIdx.x / (nwt * H);
    int t = threadIdx.x;

    __shared__ __align__(16) char smem[33536];
    int4*   pki = reinterpret_cast<int4*>(smem);                  // [576]
    float4* pkw = reinterpret_cast<float4*>(smem + 9216);         // [576]
    float*  slds = reinterpret_cast<float*>(smem + 18432);        // s[32][68]
    float*  tr  = reinterpret_cast<float*>(smem);                 // tr[128][65] (post-loop alias)

    // per-(pos,k) precompute (R2-proven logic; offsets pre-multiplied by C)
    const float* omb = omcl + (((size_t)b * H + h) * W + wt * 64) * 32;
    for (int idx = t; idx < 576; idx += 256) {
        int p = idx & 63;
        int k = idx >> 6;
        float o1 = omb[p * 32 + k];
        float o2 = omb[p * 32 + 9 + k];
        float mm = omb[p * 32 + 18 + k];
        mm = 1.f / (1.f + expf(-mm));
        float py = o1 + (float)(h + k / 3 - 1);
        float px = o2 + (float)(wt * 64 + p + k % 3 - 1);
        float y0f = floorf(py), x0f = floorf(px);
        float wy = py - y0f, wx = px - x0f;
        int y0 = (int)y0f, x0 = (int)x0f;
        bool y0v = (y0 >= 0) && (y0 < H);
        bool y1v = (y0 + 1 >= 0) && (y0 + 1 < H);
        bool x0v = (x0 >= 0) && (x0 < W);
        bool x1v = (x0 + 1 >= 0) && (x0 + 1 < W);
        int y0c = min(max(y0, 0), H - 1) * W;
        int y1c = min(max(y0 + 1, 0), H - 1) * W;
        int x0c = min(max(x0, 0), W - 1);
        int x1c = min(max(x0 + 1, 0), W - 1);
        int4 pi;
        pi.x = (y0c + x0c) * C; pi.y = (y0c + x1c) * C;
        pi.z = (y1c + x0c) * C; pi.w = (y1c + x1c) * C;
        float4 pw;
        pw.x = (y0v && x0v) ? (1.f - wy) * (1.f - wx) * mm : 0.f;
        pw.y = (y0v && x1v) ? (1.f - wy) * wx * mm : 0.f;
        pw.z = (y1v && x0v) ? wy * (1.f - wx) * mm : 0.f;
        pw.w = (y1v && x1v) ? wy * wx * mm : 0.f;
        pki[idx] = pi;
        pkw[idx] = pw;
    }
    __syncthreads();

    int og = t & 31;   // o = og*4 .. +3
    int pg = t >> 5;   // pos = pg*8 .. +7
    float acc[8][4];
#pragma unroll
    for (int p = 0; p < 8; p++)
#pragma unroll
        for (int j = 0; j < 4; j++) acc[p][j] = 0.f;

    const __bf16* xb = xcl + (size_t)b * H * W * C;
    int pc = t & 63;   // phase-1 gather position
    int cq = t >> 6;   // phase-1 channel octet (wave-uniform)

    for (int k = 0; k < 9; k++) {
        for (int ch = 0; ch < NCH; ch++) {
            // phase 1: gather s[c][pos] from channel-last bf16
            {
                int4   pi = pki[k * 64 + pc];
                float4 pw = pkw[k * 64 + pc];
                int cb = ch * 32 + cq * 8;
                uint4 u00 = *reinterpret_cast<const uint4*>(xb + pi.x + cb);
                uint4 u01 = *reinterpret_cast<const uint4*>(xb + pi.y + cb);
                uint4 u10 = *reinterpret_cast<const uint4*>(xb + pi.z + cb);
                uint4 u11 = *reinterpret_cast<const uint4*>(xb + pi.w + cb);
                bf16x8 v00 = __builtin_bit_cast(bf16x8, u00);
                bf16x8 v01 = __builtin_bit_cast(bf16x8, u01);
                bf16x8 v10 = __builtin_bit_cast(bf16x8, u10);
                bf16x8 v11 = __builtin_bit_cast(bf16x8, u11);
#pragma unroll
                for (int j = 0; j < 8; j++) {
                    float s = pw.x * (float)v00[j] + pw.y * (float)v01[j]
                            + pw.z * (float)v10[j] + pw.w * (float)v11[j];
                    slds[(cq * 8 + j) * 68 + pc] = s;
                }
            }
            __syncthreads();
            // phase 2: acc[pos][o] += s[pos][c] * wkt[k][c][o]  (R2-proven)
            const float* wkp = wkt + ((size_t)k * C + ch * 32) * OO + og * 4;
#pragma unroll 4
            for (int cc = 0; cc < 32; cc++) {
                float4 wv = *reinterpret_cast<const float4*>(wkp + (size_t)cc * OO);
                const float* sp = &slds[cc * 68 + pg * 8];
#pragma unroll
                for (int p = 0; p < 8; p++) {
                    float sv = sp[p];
                    acc[p][0] = fmaf(sv, wv.x, acc[p][0]);
                    acc[p][1] = fmaf(sv, wv.y, acc[p][1]);
                    acc[p][2] = fmaf(sv, wv.z, acc[p][2]);
                    acc[p][3] = fmaf(sv, wv.w, acc[p][3]);
                }
            }
            __syncthreads();
        }
    }

    if (CF_OUT) {
        // last __syncthreads above guarantees everyone left phase 1/2; alias tr
#pragma unroll
        for (int j = 0; j < 4; j++) {
            int o = og * 4 + j;
            float s = sc[o], hh = sh[o];
#pragma unroll
            for (int p = 0; p < 8; p++) {
                tr[o * 65 + pg * 8 + p] = fmaxf(acc[p][j] * s + hh, 0.f);
            }
        }
        __syncthreads();
        float* ob = outcf + (size_t)b * OO * H * W + (size_t)h * W + wt * 64;
        for (int i = 0; i < 32; i++) {
            int ii = i * 256 + t;
            int o = ii >> 6, p = ii & 63;
            ob[(size_t)o * H * W + p] = tr[o * 65 + p];
        }
    } else {
        __bf16* ob = outcl + (((size_t)b * H + h) * W + wt * 64) * OO;
#pragma unroll
        for (int j = 0; j < 4; j++) {
            int o = og * 4 + j;
            float s = sc[o], hh = sh[o];
#pragma unroll
            for (int p = 0; p < 8; p++) {
                float y = fmaxf(acc[p][j] * s + hh, 0.f);
                ob[(size_t)(pg * 8 + p) * OO + o] = (__bf16)y;
            }
        }
    }
}

// ---------- bilinear x2 depthwise transposed conv + residual ----------
__global__ __launch_bounds__(256) void upsample_cl_kernel(
    const __bf16* __restrict__ h1cl,  // [B][HA][WA][O] bf16
    const float* __restrict__ prex,   // [B][O][HC][WC] fp32
    const float* __restrict__ upwt,   // [16][O]
    __bf16* __restrict__ zcl)         // [B][HC][WC][O] bf16
{
    int idx = blockIdx.x * blockDim.x + threadIdx.x;
    int x  = idx & (WC - 1);
    int y  = (idx >> 8) & (HC - 1);
    int cg = (idx >> 15) & 15;
    int b  = idx >> 19;

    int sy0, iy0, sy1, iy1, sx0, ix0, sx1, ix1;
    if (y & 1) { sy0 = (y - 1) >> 1; iy0 = 2; sy1 = sy0 + 1; iy1 = 0; }
    else       { sy0 = (y >> 1) - 1; iy0 = 3; sy1 = sy0 + 1; iy1 = 1; }
    if (x & 1) { sx0 = (x - 1) >> 1; ix0 = 2; sx1 = sx0 + 1; ix1 = 0; }
    else       { sx0 = (x >> 1) - 1; ix0 = 3; sx1 = sx0 + 1; ix1 = 1; }

    int c0 = cg * 8;
    float acc[8];
    const float* pp = prex + ((size_t)b * OO + c0) * (HC * WC) + (size_t)y * WC + x;
#pragma unroll
    for (int j = 0; j < 8; j++) acc[j] = pp[(size_t)j * HC * WC];

    bool y0v = sy0 >= 0, y1v = sy1 < HA;
    bool x0v = sx0 >= 0, x1v = sx1 < WA;
    const __bf16* hb = h1cl + (size_t)b * HA * WA * OO + c0;

    auto tap = [&](int sy, int sx, int wi) {
        uint4 u = *reinterpret_cast<const uint4*>(hb + ((size_t)sy * WA + sx) * OO);
        bf16x8 v = __builtin_bit_cast(bf16x8, u);
        const float* wp = upwt + wi * OO + c0;
#pragma unroll
        for (int j = 0; j < 8; j++) acc[j] += (float)v[j] * wp[j];
    };
    if (y0v && x0v) tap(sy0, sx0, iy0 * 4 + ix0);
    if (y0v && x1v) tap(sy0, sx1, iy0 * 4 + ix1);
    if (y1v && x0v) tap(sy1, sx0, iy1 * 4 + ix0);
    if (y1v && x1v) tap(sy1, sx1, iy1 * 4 + ix1);

    bf16x8 r;
#pragma unroll
    for (int j = 0; j < 8; j++) r[j] = (__bf16)acc[j];
    *reinterpret_cast<bf16x8*>(zcl + (((size_t)b * HC + y) * WC + x) * OO + c0) = r;
}

// ---------------- launch ----------------
extern "C" void kernel_launch(void* const* d_in, const int* in_sizes, int n_in,
                              void* d_out, int out_size, void* d_ws, size_t ws_size,
                              hipStream_t stream) {
    (void)in_sizes; (void)n_in; (void)out_size; (void)ws_size;
    const float* x      = (const float*)d_in[0];
    const float* pre_x  = (const float*)d_in[1];
    const float* pwom   = (const float*)d_in[2];
    const float* pbom   = (const float*)d_in[3];
    const float* pw     = (const float*)d_in[4];
    const float* pb     = (const float*)d_in[5];
    const float* pgam   = (const float*)d_in[6];
    const float* pbet   = (const float*)d_in[7];
    const float* pmea   = (const float*)d_in[8];
    const float* pvar   = (const float*)d_in[9];
    const float* nwom   = (const float*)d_in[10];
    const float* nbom   = (const float*)d_in[11];
    const float* nw     = (const float*)d_in[12];
    const float* nb     = (const float*)d_in[13];
    const float* ngam   = (const float*)d_in[14];
    const float* nbet   = (const float*)d_in[15];
    const float* nmea   = (const float*)d_in[16];
    const float* nvar   = (const float*)d_in[17];
    const float* upw    = (const float*)d_in[18];
    float* out = (float*)d_out;

    char* wsb = (char*)d_ws;
    __bf16* xclA  = (__bf16*)(wsb + 0);          //  8,388,608 B
    __bf16* h1cl  = (__bf16*)(wsb + 8388608);    //  4,194,304
    __bf16* zcl   = (__bf16*)(wsb + 12582912);   // 16,777,216
    float*  omA   = (float*) (wsb + 29360128);   //  2,097,152
    float*  omC   = (float*) (wsb + 31457280);   //  8,388,608
    float*  womtA = (float*) (wsb + 39845888);   //    258,048
    float*  womtC = (float*) (wsb + 40103936);   //    129,024
    float*  wktA  = (float*) (wsb + 40232960);   //  1,179,648
    float*  wktC  = (float*) (wsb + 41412608);   //    589,824
    float*  upwt  = (float*) (wsb + 42002432);   //      8,192
    float*  scA   = (float*) (wsb + 42010624);
    float*  shA   = (float*) (wsb + 42011136);
    float*  scC   = (float*) (wsb + 42011648);
    float*  shC   = (float*) (wsb + 42012160);   // end ~42.0 MB

    // prepacks
    wk_transpose_kernel<<<(9*CA*OO + 255)/256, 256, 0, stream>>>(pw, wktA, CA);
    wk_transpose_kernel<<<(9*CC*OO + 255)/256, 256, 0, stream>>>(nw, wktC, CC);
    pack_womt_kernel<<<252, 256, 0, stream>>>(pwom, womtA, CA);
    pack_womt_kernel<<<126, 256, 0, stream>>>(nwom, womtC, CC);
    bn_prepack_kernel<<<1, 128, 0, stream>>>(pgam, pbet, pmea, pvar, pb, scA, shA);
    bn_prepack_kernel<<<1, 128, 0, stream>>>(ngam, nbet, nmea, nvar, nb, scC, shC);
    pack_upw_kernel<<<8, 256, 0, stream>>>(upw, upwt);
    to_cl_kernel<CA, HA*WA><<<BN2 * (CA/32) * (HA*WA/64), 256, 0, stream>>>(x, xclA);

    // stage A
    om_conv_scalar_kernel<CA, HA, WA><<<BN2 * HA * (WA/64), 256, 0, stream>>>(xclA, womtA, pbom, omA);
    dcn_scalar_cl_kernel<CA, HA, WA, false><<<BN2 * HA * (WA/64), 256, 0, stream>>>(
        xclA, omA, wktA, scA, shA, nullptr, h1cl);

    // upsample + residual
    upsample_cl_kernel<<<(BN2 * 16 * HC * WC) / 256, 256, 0, stream>>>(h1cl, pre_x, upwt, zcl);

    // stage C
    om_conv_scalar_kernel<CC, HC, WC><<<BN2 * HC * (WC/64), 256, 0, stream>>>(zcl, womtC, nbom, omC);
    dcn_scalar_cl_kernel<CC, HC, WC, true><<<BN2 * HC * (WC/64), 256, 0, stream>>>(
        zcl, omC, wktC, scC, shC, out, nullptr);
}

// Round 6
// 819.502 us; speedup vs baseline: 2.0245x; 1.4084x over previous
//
#include <hip/hip_runtime.h>
#include <hip/hip_bf16.h>
#include <math.h>

typedef __bf16 bf16x8 __attribute__((ext_vector_type(8)));
typedef float  f32x4  __attribute__((ext_vector_type(4)));

static constexpr int BN2 = 2;
static constexpr int CA = 256, HA = 64, WA = 128;   // stage A input
static constexpr int OO = 128;                      // output channels
static constexpr int HC = 128, WC = 256, CC = 128;  // stage C

// ---------- pack weights into MFMA B-fragment layout: [9][C/32][OT][64][8] bf16 ----------
__global__ void pack_w_kernel(const float* __restrict__ w, __bf16* __restrict__ out,
                              int Cin, int OT, int Oreal) {
    int NCH = Cin / 32;
    int idx = blockIdx.x * blockDim.x + threadIdx.x;
    int total = 9 * NCH * OT * 512;
    if (idx >= total) return;
    int j    = idx & 7;
    int lane = (idx >> 3) & 63;
    int ot   = (idx >> 9) % OT;
    int rest = (idx >> 9) / OT;
    int ch = rest % NCH;
    int k  = rest / NCH;
    int o = ot * 16 + (lane & 15);
    int c = ch * 32 + (lane >> 4) * 8 + j;
    float v = (o < Oreal) ? w[((size_t)o * Cin + c) * 9 + k] : 0.f;
    out[idx] = (__bf16)v;
}

// ---------- pack om weights fp32: womt[9][C/8][28][8] ----------
__global__ void pack_womt_kernel(const float* __restrict__ w, float* __restrict__ out, int Cin) {
    int C8 = Cin / 8;
    int idx = blockIdx.x * blockDim.x + threadIdx.x;
    int total = 9 * C8 * 28 * 8;
    if (idx >= total) return;
    int j  = idx & 7;
    int oc = (idx >> 3) % 28;
    int c8 = (idx / (8 * 28)) % C8;
    int k  = idx / (8 * 28 * C8);
    float v = (oc < 27) ? w[((size_t)oc * Cin + (c8 * 8 + j)) * 9 + k] : 0.f;
    out[idx] = v;
}

// ---------- NCHW fp32 -> NHWC bf16 (LDS tile transpose) ----------
template<int C, int HW>
__global__ __launch_bounds__(256) void to_cl_kernel(const float* __restrict__ x,
                                                    __bf16* __restrict__ xcl) {
    constexpr int NCB = C / 32;
    constexpr int NPB = HW / 64;
    int blk = blockIdx.x;
    int pblk = blk % NPB;
    int cblk = (blk / NPB) % NCB;
    int b = blk / (NPB * NCB);
    int t = threadIdx.x;
    __shared__ float st[32][65];
    int r = t >> 6, q = t & 63;
#pragma unroll
    for (int i = 0; i < 8; i++) {
        int c = cblk * 32 + i * 4 + r;
        st[i * 4 + r][q] = x[((size_t)b * C + c) * HW + pblk * 64 + q];
    }
    __syncthreads();
    int p = t >> 2, cq = t & 3;
    bf16x8 v;
#pragma unroll
    for (int j = 0; j < 8; j++) v[j] = (__bf16)st[cq * 8 + j][p];
    *reinterpret_cast<bf16x8*>(xcl + ((size_t)b * HW + pblk * 64 + p) * C + cblk * 32 + cq * 8) = v;
}

// ---------- fold bias+BN into per-o scale/shift ----------
__global__ void bn_prepack_kernel(const float* __restrict__ g,  const float* __restrict__ be,
                                  const float* __restrict__ mu, const float* __restrict__ va,
                                  const float* __restrict__ bi,
                                  float* __restrict__ sc, float* __restrict__ sh) {
    int i = blockIdx.x * blockDim.x + threadIdx.x;
    if (i >= OO) return;
    float s = g[i] * rsqrtf(va[i] + 1e-5f);
    sc[i] = s;
    sh[i] = (bi[i] - mu[i]) * s + be[i];
}

// ---------- upw[O][4][4] -> upwt[16][O] ----------
__global__ void pack_upw_kernel(const float* __restrict__ upw, float* __restrict__ upwt) {
    int idx = blockIdx.x * blockDim.x + threadIdx.x;
    if (idx >= 16 * OO) return;
    int i = idx >> 7;
    int o = idx & 127;
    upwt[i * OO + o] = upw[o * 16 + i];
}

// ---------- scalar om-conv: channel-last in, channel-last om out (proven r5) ----------
template<int C, int H, int W>
__global__ __launch_bounds__(256) void om_conv_scalar_kernel(
    const __bf16* __restrict__ xcl,   // [B][H][W][C]
    const float* __restrict__ womt,   // [9][C/8][28][8] fp32
    const float* __restrict__ bom,    // [27]
    float* __restrict__ omcl)         // [B][H][W][32]
{
    constexpr int C8 = C / 8;
    const int nwt = W / 64;
    int wt = blockIdx.x % nwt;
    int h  = (blockIdx.x / nwt) % H;
    int b  = blockIdx.x / (nwt * H);
    int t = threadIdx.x;
    int pc = t & 63;
    int grp = t >> 6;
    int oc0 = grp * 7;
    int noc = (grp < 3) ? 7 : 6;
    int w = wt * 64 + pc;

    float acc[7];
#pragma unroll
    for (int i = 0; i < 7; i++) acc[i] = 0.f;

    const __bf16* xb = xcl + (size_t)b * H * W * C;
    for (int k = 0; k < 9; k++) {
        int y = h + k / 3 - 1, xx = w + k % 3 - 1;
        bool valid = (y >= 0) && (y < H) && (xx >= 0) && (xx < W);
        if (!valid) continue;
        const __bf16* px = xb + ((size_t)y * W + xx) * C;
        const float* wkb = womt + (size_t)k * C8 * 28 * 8;
        for (int c8 = 0; c8 < C8; c8++) {
            bf16x8 xv = *reinterpret_cast<const bf16x8*>(px + c8 * 8);
            float xf[8];
#pragma unroll
            for (int j = 0; j < 8; j++) xf[j] = (float)xv[j];
            const float* wrow = wkb + ((size_t)c8 * 28 + oc0) * 8;
#pragma unroll
            for (int i = 0; i < 7; i++) {
                if (i < noc) {
#pragma unroll
                    for (int j = 0; j < 8; j++)
                        acc[i] = fmaf(xf[j], wrow[i * 8 + j], acc[i]);
                }
            }
        }
    }
    float* ob = omcl + (((size_t)b * H + h) * W + w) * 32;
    for (int i = 0; i < noc; i++) ob[oc0 + i] = acc[i] + bom[oc0 + i];
}

// ---------- DCN: proven phase-1 gather into LDS; phase-2 = MFMA (the one new variable) ----------
template<int C, int H, int W, bool CF_OUT>
__global__ __launch_bounds__(256) void dcn_mfma2_kernel(
    const __bf16* __restrict__ xcl,  // [B][H][W][C]
    const float* __restrict__ omcl,  // [B][H][W][32]
    const __bf16* __restrict__ wkp,  // [9][C/32][8][64][8] bf16 (pack_w)
    const float* __restrict__ sc, const float* __restrict__ sh,
    float* __restrict__ outcf,       // CF_OUT: [B][O][H][W] fp32
    __bf16* __restrict__ outcl)      // else:   [B][H][W][O] bf16
{
    constexpr int NCH = C / 32;
    constexpr int SS = 69;           // slds stride: odd -> phase-2 reads 2-way (free)
    const int nwt = W / 64;
    int wt = blockIdx.x % nwt;
    int h  = (blockIdx.x / nwt) % H;
    int b  = blockIdx.x / (nwt * H);
    int t = threadIdx.x;
    int wave = t >> 6, lane = t & 63;
    int row = lane & 15, kg = lane >> 4;

    __shared__ __align__(16) char smem[33536];
    int4*   pki  = reinterpret_cast<int4*>(smem);                 // [576]
    float4* pkw  = reinterpret_cast<float4*>(smem + 9216);        // [576]
    float*  slds = reinterpret_cast<float*>(smem + 18432);        // [32][SS]
    float*  tr   = reinterpret_cast<float*>(smem);                // tr[128][65] (post-loop alias)

    // per-(pos,k) precompute (proven r5)
    const float* omb = omcl + (((size_t)b * H + h) * W + wt * 64) * 32;
    for (int idx = t; idx < 576; idx += 256) {
        int p = idx & 63;
        int k = idx >> 6;
        float o1 = omb[p * 32 + k];
        float o2 = omb[p * 32 + 9 + k];
        float mm = omb[p * 32 + 18 + k];
        mm = 1.f / (1.f + expf(-mm));
        float py = o1 + (float)(h + k / 3 - 1);
        float px = o2 + (float)(wt * 64 + p + k % 3 - 1);
        float y0f = floorf(py), x0f = floorf(px);
        float wy = py - y0f, wx = px - x0f;
        int y0 = (int)y0f, x0 = (int)x0f;
        bool y0v = (y0 >= 0) && (y0 < H);
        bool y1v = (y0 + 1 >= 0) && (y0 + 1 < H);
        bool x0v = (x0 >= 0) && (x0 < W);
        bool x1v = (x0 + 1 >= 0) && (x0 + 1 < W);
        int y0c = min(max(y0, 0), H - 1) * W;
        int y1c = min(max(y0 + 1, 0), H - 1) * W;
        int x0c = min(max(x0, 0), W - 1);
        int x1c = min(max(x0 + 1, 0), W - 1);
        int4 pi;
        pi.x = (y0c + x0c) * C; pi.y = (y0c + x1c) * C;
        pi.z = (y1c + x0c) * C; pi.w = (y1c + x1c) * C;
        float4 pw;
        pw.x = (y0v && x0v) ? (1.f - wy) * (1.f - wx) * mm : 0.f;
        pw.y = (y0v && x1v) ? (1.f - wy) * wx * mm : 0.f;
        pw.z = (y1v && x0v) ? wy * (1.f - wx) * mm : 0.f;
        pw.w = (y1v && x1v) ? wy * wx * mm : 0.f;
        pki[idx] = pi;
        pkw[idx] = pw;
    }
    __syncthreads();

    f32x4 acc[8];
#pragma unroll
    for (int i = 0; i < 8; i++) acc[i] = {0.f, 0.f, 0.f, 0.f};

    const __bf16* xb = xcl + (size_t)b * H * W * C;
    int pc = t & 63;   // phase-1 gather position
    int cq = t >> 6;   // phase-1 channel octet (wave-uniform)

    for (int k = 0; k < 9; k++) {
        for (int ch = 0; ch < NCH; ch++) {
            // phase 1 (proven r5): gather s[c][pos] fp32 into LDS
            {
                int4   pi = pki[k * 64 + pc];
                float4 pw = pkw[k * 64 + pc];
                int cb = ch * 32 + cq * 8;
                uint4 u00 = *reinterpret_cast<const uint4*>(xb + pi.x + cb);
                uint4 u01 = *reinterpret_cast<const uint4*>(xb + pi.y + cb);
                uint4 u10 = *reinterpret_cast<const uint4*>(xb + pi.z + cb);
                uint4 u11 = *reinterpret_cast<const uint4*>(xb + pi.w + cb);
                bf16x8 v00 = __builtin_bit_cast(bf16x8, u00);
                bf16x8 v01 = __builtin_bit_cast(bf16x8, u01);
                bf16x8 v10 = __builtin_bit_cast(bf16x8, u10);
                bf16x8 v11 = __builtin_bit_cast(bf16x8, u11);
#pragma unroll
                for (int j = 0; j < 8; j++) {
                    float s = pw.x * (float)v00[j] + pw.y * (float)v01[j]
                            + pw.z * (float)v10[j] + pw.w * (float)v11[j];
                    slds[(cq * 8 + j) * SS + pc] = s;
                }
            }
            __syncthreads();
            // phase 2 (NEW): MFMA. A-frag from slds, B-frag from pack_w buffer.
            {
                bf16x8 a;
#pragma unroll
                for (int j = 0; j < 8; j++)
                    a[j] = (__bf16)slds[(kg * 8 + j) * SS + wave * 16 + row];
                const __bf16* wbc = wkp + ((size_t)k * NCH + ch) * 4096 + lane * 8;
#pragma unroll
                for (int ot = 0; ot < 8; ot++) {
                    bf16x8 bv = *reinterpret_cast<const bf16x8*>(wbc + ot * 512);
                    acc[ot] = __builtin_amdgcn_mfma_f32_16x16x32_bf16(a, bv, acc[ot], 0, 0, 0);
                }
            }
            __syncthreads();
        }
    }

    // epilogue with MFMA D mapping: col = lane&15 -> o, row = kg*4+j -> pos
    if (CF_OUT) {
        __syncthreads();
#pragma unroll
        for (int ot = 0; ot < 8; ot++) {
            int o = ot * 16 + row;
            float s = sc[o], hh = sh[o];
            int p = wave * 16 + kg * 4;
#pragma unroll
            for (int j = 0; j < 4; j++) {
                tr[o * 65 + p + j] = fmaxf(acc[ot][j] * s + hh, 0.f);
            }
        }
        __syncthreads();
        float* ob = outcf + (size_t)b * OO * H * W + (size_t)h * W + wt * 64;
        for (int i = 0; i < 32; i++) {
            int ii = i * 256 + t;
            int o = ii >> 6, p = ii & 63;
            ob[(size_t)o * H * W + p] = tr[o * 65 + p];
        }
    } else {
        __bf16* ob = outcl + (((size_t)b * H + h) * W + wt * 64) * OO;
        int p0 = wave * 16 + kg * 4;
#pragma unroll
        for (int ot = 0; ot < 8; ot++) {
            int o = ot * 16 + row;
            float s = sc[o], hh = sh[o];
#pragma unroll
            for (int j = 0; j < 4; j++) {
                float y = fmaxf(acc[ot][j] * s + hh, 0.f);
                ob[(size_t)(p0 + j) * OO + o] = (__bf16)y;
            }
        }
    }
}

// ---------- bilinear x2 depthwise transposed conv + residual ----------
__global__ __launch_bounds__(256) void upsample_cl_kernel(
    const __bf16* __restrict__ h1cl,  // [B][HA][WA][O] bf16
    const float* __restrict__ prex,   // [B][O][HC][WC] fp32
    const float* __restrict__ upwt,   // [16][O]
    __bf16* __restrict__ zcl)         // [B][HC][WC][O] bf16
{
    int idx = blockIdx.x * blockDim.x + threadIdx.x;
    int x  = idx & (WC - 1);
    int y  = (idx >> 8) & (HC - 1);
    int cg = (idx >> 15) & 15;
    int b  = idx >> 19;

    int sy0, iy0, sy1, iy1, sx0, ix0, sx1, ix1;
    if (y & 1) { sy0 = (y - 1) >> 1; iy0 = 2; sy1 = sy0 + 1; iy1 = 0; }
    else       { sy0 = (y >> 1) - 1; iy0 = 3; sy1 = sy0 + 1; iy1 = 1; }
    if (x & 1) { sx0 = (x - 1) >> 1; ix0 = 2; sx1 = sx0 + 1; ix1 = 0; }
    else       { sx0 = (x >> 1) - 1; ix0 = 3; sx1 = sx0 + 1; ix1 = 1; }

    int c0 = cg * 8;
    float acc[8];
    const float* pp = prex + ((size_t)b * OO + c0) * (HC * WC) + (size_t)y * WC + x;
#pragma unroll
    for (int j = 0; j < 8; j++) acc[j] = pp[(size_t)j * HC * WC];

    bool y0v = sy0 >= 0, y1v = sy1 < HA;
    bool x0v = sx0 >= 0, x1v = sx1 < WA;
    const __bf16* hb = h1cl + (size_t)b * HA * WA * OO + c0;

    auto tap = [&](int sy, int sx, int wi) {
        uint4 u = *reinterpret_cast<const uint4*>(hb + ((size_t)sy * WA + sx) * OO);
        bf16x8 v = __builtin_bit_cast(bf16x8, u);
        const float* wp = upwt + wi * OO + c0;
#pragma unroll
        for (int j = 0; j < 8; j++) acc[j] += (float)v[j] * wp[j];
    };
    if (y0v && x0v) tap(sy0, sx0, iy0 * 4 + ix0);
    if (y0v && x1v) tap(sy0, sx1, iy0 * 4 + ix1);
    if (y1v && x0v) tap(sy1, sx0, iy1 * 4 + ix0);
    if (y1v && x1v) tap(sy1, sx1, iy1 * 4 + ix1);

    bf16x8 r;
#pragma unroll
    for (int j = 0; j < 8; j++) r[j] = (__bf16)acc[j];
    *reinterpret_cast<bf16x8*>(zcl + (((size_t)b * HC + y) * WC + x) * OO + c0) = r;
}

// ---------------- launch ----------------
extern "C" void kernel_launch(void* const* d_in, const int* in_sizes, int n_in,
                              void* d_out, int out_size, void* d_ws, size_t ws_size,
                              hipStream_t stream) {
    (void)in_sizes; (void)n_in; (void)out_size; (void)ws_size;
    const float* x      = (const float*)d_in[0];
    const float* pre_x  = (const float*)d_in[1];
    const float* pwom   = (const float*)d_in[2];
    const float* pbom   = (const float*)d_in[3];
    const float* pw     = (const float*)d_in[4];
    const float* pb     = (const float*)d_in[5];
    const float* pgam   = (const float*)d_in[6];
    const float* pbet   = (const float*)d_in[7];
    const float* pmea   = (const float*)d_in[8];
    const float* pvar   = (const float*)d_in[9];
    const float* nwom   = (const float*)d_in[10];
    const float* nbom   = (const float*)d_in[11];
    const float* nw     = (const float*)d_in[12];
    const float* nb     = (const float*)d_in[13];
    const float* ngam   = (const float*)d_in[14];
    const float* nbet   = (const float*)d_in[15];
    const float* nmea   = (const float*)d_in[16];
    const float* nvar   = (const float*)d_in[17];
    const float* upw    = (const float*)d_in[18];
    float* out = (float*)d_out;

    char* wsb = (char*)d_ws;
    __bf16* xclA  = (__bf16*)(wsb + 0);          //  8,388,608 B
    __bf16* h1cl  = (__bf16*)(wsb + 8388608);    //  4,194,304
    __bf16* zcl   = (__bf16*)(wsb + 12582912);   // 16,777,216
    float*  omA   = (float*) (wsb + 29360128);   //  2,097,152
    float*  omC   = (float*) (wsb + 31457280);   //  8,388,608
    __bf16* wkAp  = (__bf16*)(wsb + 39845888);   //    589,824
    __bf16* wkCp  = (__bf16*)(wsb + 40435712);   //    294,912
    float*  womtA = (float*) (wsb + 40730624);   //    258,048
    float*  womtC = (float*) (wsb + 40988672);   //    129,024
    float*  upwt  = (float*) (wsb + 41117696);   //      8,192
    float*  scA   = (float*) (wsb + 41125888);
    float*  shA   = (float*) (wsb + 41126400);
    float*  scC   = (float*) (wsb + 41126912);
    float*  shC   = (float*) (wsb + 41127424);   // end ~41.1 MB

    // prepacks
    pack_w_kernel<<<1152, 256, 0, stream>>>(pw, wkAp, CA, 8, 128);
    pack_w_kernel<<<576, 256, 0, stream>>>(nw, wkCp, CC, 8, 128);
    pack_womt_kernel<<<252, 256, 0, stream>>>(pwom, womtA, CA);
    pack_womt_kernel<<<126, 256, 0, stream>>>(nwom, womtC, CC);
    bn_prepack_kernel<<<1, 128, 0, stream>>>(pgam, pbet, pmea, pvar, pb, scA, shA);
    bn_prepack_kernel<<<1, 128, 0, stream>>>(ngam, nbet, nmea, nvar, nb, scC, shC);
    pack_upw_kernel<<<8, 256, 0, stream>>>(upw, upwt);
    to_cl_kernel<CA, HA*WA><<<BN2 * (CA/32) * (HA*WA/64), 256, 0, stream>>>(x, xclA);

    // stage A
    om_conv_scalar_kernel<CA, HA, WA><<<BN2 * HA * (WA/64), 256, 0, stream>>>(xclA, womtA, pbom, omA);
    dcn_mfma2_kernel<CA, HA, WA, false><<<BN2 * HA * (WA/64), 256, 0, stream>>>(
        xclA, omA, wkAp, scA, shA, nullptr, h1cl);

    // upsample + residual
    upsample_cl_kernel<<<(BN2 * 16 * HC * WC) / 256, 256, 0, stream>>>(h1cl, pre_x, upwt, zcl);

    // stage C
    om_conv_scalar_kernel<CC, HC, WC><<<BN2 * HC * (WC/64), 256, 0, stream>>>(zcl, womtC, nbom, omC);
    dcn_mfma2_kernel<CC, HC, WC, true><<<BN2 * HC * (WC/64), 256, 0, stream>>>(
        zcl, omC, wkCp, scC, shC, out, nullptr);
}

// Round 7
// 305.693 us; speedup vs baseline: 5.4274x; 2.6808x over previous
//
#include <hip/hip_runtime.h>
#include <hip/hip_bf16.h>
#include <math.h>

typedef __bf16 bf16x8 __attribute__((ext_vector_type(8)));
typedef float  f32x4  __attribute__((ext_vector_type(4)));

static constexpr int BN2 = 2;
static constexpr int CA = 256, HA = 64, WA = 128;   // stage A input
static constexpr int OO = 128;                      // output channels
static constexpr int HC = 128, WC = 256, CC = 128;  // stage C

// ---------- pack weights into MFMA B-fragment layout: [9][C/32][OT][64][8] bf16 ----------
__global__ void pack_w_kernel(const float* __restrict__ w, __bf16* __restrict__ out,
                              int Cin, int OT, int Oreal) {
    int NCH = Cin / 32;
    int idx = blockIdx.x * blockDim.x + threadIdx.x;
    int total = 9 * NCH * OT * 512;
    if (idx >= total) return;
    int j    = idx & 7;
    int lane = (idx >> 3) & 63;
    int ot   = (idx >> 9) % OT;
    int rest = (idx >> 9) / OT;
    int ch = rest % NCH;
    int k  = rest / NCH;
    int o = ot * 16 + (lane & 15);
    int c = ch * 32 + (lane >> 4) * 8 + j;
    float v = (o < Oreal) ? w[((size_t)o * Cin + c) * 9 + k] : 0.f;
    out[idx] = (__bf16)v;
}

// ---------- NCHW fp32 -> NHWC bf16 (LDS tile transpose) ----------
template<int C, int HW>
__global__ __launch_bounds__(256) void to_cl_kernel(const float* __restrict__ x,
                                                    __bf16* __restrict__ xcl) {
    constexpr int NCB = C / 32;
    constexpr int NPB = HW / 64;
    int blk = blockIdx.x;
    int pblk = blk % NPB;
    int cblk = (blk / NPB) % NCB;
    int b = blk / (NPB * NCB);
    int t = threadIdx.x;
    __shared__ float st[32][65];
    int r = t >> 6, q = t & 63;
#pragma unroll
    for (int i = 0; i < 8; i++) {
        int c = cblk * 32 + i * 4 + r;
        st[i * 4 + r][q] = x[((size_t)b * C + c) * HW + pblk * 64 + q];
    }
    __syncthreads();
    int p = t >> 2, cq = t & 3;
    bf16x8 v;
#pragma unroll
    for (int j = 0; j < 8; j++) v[j] = (__bf16)st[cq * 8 + j][p];
    *reinterpret_cast<bf16x8*>(xcl + ((size_t)b * HW + pblk * 64 + p) * C + cblk * 32 + cq * 8) = v;
}

// ---------- fold bias+BN into per-o scale/shift ----------
__global__ void bn_prepack_kernel(const float* __restrict__ g,  const float* __restrict__ be,
                                  const float* __restrict__ mu, const float* __restrict__ va,
                                  const float* __restrict__ bi,
                                  float* __restrict__ sc, float* __restrict__ sh) {
    int i = blockIdx.x * blockDim.x + threadIdx.x;
    if (i >= OO) return;
    float s = g[i] * rsqrtf(va[i] + 1e-5f);
    sc[i] = s;
    sh[i] = (bi[i] - mu[i]) * s + be[i];
}

// ---------- upw[O][4][4] -> upwt[16][O] ----------
__global__ void pack_upw_kernel(const float* __restrict__ upw, float* __restrict__ upwt) {
    int idx = blockIdx.x * blockDim.x + threadIdx.x;
    if (idx >= 16 * OO) return;
    int i = idx >> 7;
    int o = idx & 127;
    upwt[i * OO + o] = upw[o * 16 + i];
}

// ---------- om-conv as MFMA with window staging (proven A-read/B-frag/D-map patterns) ----------
template<int C, int H, int W>
__global__ __launch_bounds__(256) void om_mfma_kernel(
    const __bf16* __restrict__ xcl,   // [B][H][W][C]
    const __bf16* __restrict__ womp,  // [9][C/32][2][64][8] bf16
    const float* __restrict__ bom,    // [27]
    float* __restrict__ omcl)         // [B][H][W][32]
{
    constexpr int NCH = C / 32;
    constexpr int WS = 201;           // win stride: 8*WS mod 32 = 8 -> kg groups spread banks
    const int nwt = W / 64;
    int wt = blockIdx.x % nwt;
    int h  = (blockIdx.x / nwt) % H;
    int b  = blockIdx.x / (nwt * H);
    int t = threadIdx.x;
    int wave = t >> 6, lane = t & 63;
    int row = lane & 15, kg = lane >> 4;

    __shared__ float win[32 * WS];    // [c within chunk][3*66 halo window]

    f32x4 acc0 = {0.f, 0.f, 0.f, 0.f};
    f32x4 acc1 = {0.f, 0.f, 0.f, 0.f};
    const __bf16* xb = xcl + (size_t)b * H * W * C;

    for (int ch = 0; ch < NCH; ch++) {
        // stage 3x66 pixel window (zero-pad masked) for this 32-channel chunk
        for (int i = 0; i < 4; i++) {
            int idx = i * 256 + t;
            if (idx < 792) {
                int cq  = idx & 3;
                int pix = idx >> 2;           // 0..197 = ry*66+rx
                int ry = pix / 66, rx = pix % 66;
                int y = h + ry - 1, xx = wt * 64 + rx - 1;
                bool valid = (y >= 0) && (y < H) && (xx >= 0) && (xx < W);
                int yc = min(max(y, 0), H - 1), xc = min(max(xx, 0), W - 1);
                uint4 u = *reinterpret_cast<const uint4*>(
                    xb + ((size_t)yc * W + xc) * C + ch * 32 + cq * 8);
                if (!valid) { u.x = 0; u.y = 0; u.z = 0; u.w = 0; }
                bf16x8 v = __builtin_bit_cast(bf16x8, u);
#pragma unroll
                for (int j = 0; j < 8; j++)
                    win[(cq * 8 + j) * WS + pix] = (float)v[j];
            }
        }
        __syncthreads();
#pragma unroll
        for (int k = 0; k < 9; k++) {
            int off = (k / 3) * 66 + (k % 3) + wave * 16 + row;
            bf16x8 a;
#pragma unroll
            for (int j = 0; j < 8; j++)
                a[j] = (__bf16)win[(kg * 8 + j) * WS + off];
            const __bf16* wbc = womp + ((size_t)k * NCH + ch) * 1024 + lane * 8;
            bf16x8 b0 = *reinterpret_cast<const bf16x8*>(wbc);
            bf16x8 b1 = *reinterpret_cast<const bf16x8*>(wbc + 512);
            acc0 = __builtin_amdgcn_mfma_f32_16x16x32_bf16(a, b0, acc0, 0, 0, 0);
            acc1 = __builtin_amdgcn_mfma_f32_16x16x32_bf16(a, b1, acc1, 0, 0, 0);
        }
        __syncthreads();
    }

    // D map (r6-proven): oc = tile*16 + row, pos = wave*16 + kg*4 + j
    float* ob = omcl + (((size_t)b * H + h) * W + wt * 64 + wave * 16 + kg * 4) * 32;
    float bb0 = bom[row];
#pragma unroll
    for (int j = 0; j < 4; j++)
        ob[(size_t)j * 32 + row] = acc0[j] + bb0;
    if (row < 11) {
        float bb1 = bom[16 + row];
#pragma unroll
        for (int j = 0; j < 4; j++)
            ob[(size_t)j * 32 + 16 + row] = acc1[j] + bb1;
    }
}

// ---------- DCN: proven phase-1 gather into LDS; phase-2 MFMA (r6-proven) ----------
template<int C, int H, int W, bool CF_OUT>
__global__ __launch_bounds__(256) void dcn_mfma2_kernel(
    const __bf16* __restrict__ xcl,  // [B][H][W][C]
    const float* __restrict__ omcl,  // [B][H][W][32]
    const __bf16* __restrict__ wkp,  // [9][C/32][8][64][8] bf16 (pack_w)
    const float* __restrict__ sc, const float* __restrict__ sh,
    float* __restrict__ outcf,       // CF_OUT: [B][O][H][W] fp32
    __bf16* __restrict__ outcl)      // else:   [B][H][W][O] bf16
{
    constexpr int NCH = C / 32;
    constexpr int SS = 69;           // slds stride: odd -> phase-2 reads 2-way (free)
    const int nwt = W / 64;
    int wt = blockIdx.x % nwt;
    int h  = (blockIdx.x / nwt) % H;
    int b  = blockIdx.x / (nwt * H);
    int t = threadIdx.x;
    int wave = t >> 6, lane = t & 63;
    int row = lane & 15, kg = lane >> 4;

    __shared__ __align__(16) char smem[33536];
    int4*   pki  = reinterpret_cast<int4*>(smem);                 // [576]
    float4* pkw  = reinterpret_cast<float4*>(smem + 9216);        // [576]
    float*  slds = reinterpret_cast<float*>(smem + 18432);        // [32][SS]
    float*  tr   = reinterpret_cast<float*>(smem);                // tr[128][65] (post-loop alias)

    // per-(pos,k) precompute (proven r5)
    const float* omb = omcl + (((size_t)b * H + h) * W + wt * 64) * 32;
    for (int idx = t; idx < 576; idx += 256) {
        int p = idx & 63;
        int k = idx >> 6;
        float o1 = omb[p * 32 + k];
        float o2 = omb[p * 32 + 9 + k];
        float mm = omb[p * 32 + 18 + k];
        mm = 1.f / (1.f + expf(-mm));
        float py = o1 + (float)(h + k / 3 - 1);
        float px = o2 + (float)(wt * 64 + p + k % 3 - 1);
        float y0f = floorf(py), x0f = floorf(px);
        float wy = py - y0f, wx = px - x0f;
        int y0 = (int)y0f, x0 = (int)x0f;
        bool y0v = (y0 >= 0) && (y0 < H);
        bool y1v = (y0 + 1 >= 0) && (y0 + 1 < H);
        bool x0v = (x0 >= 0) && (x0 < W);
        bool x1v = (x0 + 1 >= 0) && (x0 + 1 < W);
        int y0c = min(max(y0, 0), H - 1) * W;
        int y1c = min(max(y0 + 1, 0), H - 1) * W;
        int x0c = min(max(x0, 0), W - 1);
        int x1c = min(max(x0 + 1, 0), W - 1);
        int4 pi;
        pi.x = (y0c + x0c) * C; pi.y = (y0c + x1c) * C;
        pi.z = (y1c + x0c) * C; pi.w = (y1c + x1c) * C;
        float4 pw;
        pw.x = (y0v && x0v) ? (1.f - wy) * (1.f - wx) * mm : 0.f;
        pw.y = (y0v && x1v) ? (1.f - wy) * wx * mm : 0.f;
        pw.z = (y1v && x0v) ? wy * (1.f - wx) * mm : 0.f;
        pw.w = (y1v && x1v) ? wy * wx * mm : 0.f;
        pki[idx] = pi;
        pkw[idx] = pw;
    }
    __syncthreads();

    f32x4 acc[8];
#pragma unroll
    for (int i = 0; i < 8; i++) acc[i] = {0.f, 0.f, 0.f, 0.f};

    const __bf16* xb = xcl + (size_t)b * H * W * C;
    int pc = t & 63;   // phase-1 gather position
    int cq = t >> 6;   // phase-1 channel octet (wave-uniform)

    for (int k = 0; k < 9; k++) {
        for (int ch = 0; ch < NCH; ch++) {
            // phase 1 (proven r5): gather s[c][pos] fp32 into LDS
            {
                int4   pi = pki[k * 64 + pc];
                float4 pw = pkw[k * 64 + pc];
                int cb = ch * 32 + cq * 8;
                uint4 u00 = *reinterpret_cast<const uint4*>(xb + pi.x + cb);
                uint4 u01 = *reinterpret_cast<const uint4*>(xb + pi.y + cb);
                uint4 u10 = *reinterpret_cast<const uint4*>(xb + pi.z + cb);
                uint4 u11 = *reinterpret_cast<const uint4*>(xb + pi.w + cb);
                bf16x8 v00 = __builtin_bit_cast(bf16x8, u00);
                bf16x8 v01 = __builtin_bit_cast(bf16x8, u01);
                bf16x8 v10 = __builtin_bit_cast(bf16x8, u10);
                bf16x8 v11 = __builtin_bit_cast(bf16x8, u11);
#pragma unroll
                for (int j = 0; j < 8; j++) {
                    float s = pw.x * (float)v00[j] + pw.y * (float)v01[j]
                            + pw.z * (float)v10[j] + pw.w * (float)v11[j];
                    slds[(cq * 8 + j) * SS + pc] = s;
                }
            }
            __syncthreads();
            // phase 2 (proven r6): MFMA. A-frag from slds, B-frag from pack_w buffer.
            {
                bf16x8 a;
#pragma unroll
                for (int j = 0; j < 8; j++)
                    a[j] = (__bf16)slds[(kg * 8 + j) * SS + wave * 16 + row];
                const __bf16* wbc = wkp + ((size_t)k * NCH + ch) * 4096 + lane * 8;
#pragma unroll
                for (int ot = 0; ot < 8; ot++) {
                    bf16x8 bv = *reinterpret_cast<const bf16x8*>(wbc + ot * 512);
                    acc[ot] = __builtin_amdgcn_mfma_f32_16x16x32_bf16(a, bv, acc[ot], 0, 0, 0);
                }
            }
            __syncthreads();
        }
    }

    // epilogue with MFMA D mapping: col = lane&15 -> o, row = kg*4+j -> pos
    if (CF_OUT) {
        __syncthreads();
#pragma unroll
        for (int ot = 0; ot < 8; ot++) {
            int o = ot * 16 + row;
            float s = sc[o], hh = sh[o];
            int p = wave * 16 + kg * 4;
#pragma unroll
            for (int j = 0; j < 4; j++) {
                tr[o * 65 + p + j] = fmaxf(acc[ot][j] * s + hh, 0.f);
            }
        }
        __syncthreads();
        float* ob = outcf + (size_t)b * OO * H * W + (size_t)h * W + wt * 64;
        for (int i = 0; i < 32; i++) {
            int ii = i * 256 + t;
            int o = ii >> 6, p = ii & 63;
            ob[(size_t)o * H * W + p] = tr[o * 65 + p];
        }
    } else {
        __bf16* ob = outcl + (((size_t)b * H + h) * W + wt * 64) * OO;
        int p0 = wave * 16 + kg * 4;
#pragma unroll
        for (int ot = 0; ot < 8; ot++) {
            int o = ot * 16 + row;
            float s = sc[o], hh = sh[o];
#pragma unroll
            for (int j = 0; j < 4; j++) {
                float y = fmaxf(acc[ot][j] * s + hh, 0.f);
                ob[(size_t)(p0 + j) * OO + o] = (__bf16)y;
            }
        }
    }
}

// ---------- bilinear x2 depthwise transposed conv + residual ----------
__global__ __launch_bounds__(256) void upsample_cl_kernel(
    const __bf16* __restrict__ h1cl,  // [B][HA][WA][O] bf16
    const float* __restrict__ prex,   // [B][O][HC][WC] fp32
    const float* __restrict__ upwt,   // [16][O]
    __bf16* __restrict__ zcl)         // [B][HC][WC][O] bf16
{
    int idx = blockIdx.x * blockDim.x + threadIdx.x;
    int x  = idx & (WC - 1);
    int y  = (idx >> 8) & (HC - 1);
    int cg = (idx >> 15) & 15;
    int b  = idx >> 19;

    int sy0, iy0, sy1, iy1, sx0, ix0, sx1, ix1;
    if (y & 1) { sy0 = (y - 1) >> 1; iy0 = 2; sy1 = sy0 + 1; iy1 = 0; }
    else       { sy0 = (y >> 1) - 1; iy0 = 3; sy1 = sy0 + 1; iy1 = 1; }
    if (x & 1) { sx0 = (x - 1) >> 1; ix0 = 2; sx1 = sx0 + 1; ix1 = 0; }
    else       { sx0 = (x >> 1) - 1; ix0 = 3; sx1 = sx0 + 1; ix1 = 1; }

    int c0 = cg * 8;
    float acc[8];
    const float* pp = prex + ((size_t)b * OO + c0) * (HC * WC) + (size_t)y * WC + x;
#pragma unroll
    for (int j = 0; j < 8; j++) acc[j] = pp[(size_t)j * HC * WC];

    bool y0v = sy0 >= 0, y1v = sy1 < HA;
    bool x0v = sx0 >= 0, x1v = sx1 < WA;
    const __bf16* hb = h1cl + (size_t)b * HA * WA * OO + c0;

    auto tap = [&](int sy, int sx, int wi) {
        uint4 u = *reinterpret_cast<const uint4*>(hb + ((size_t)sy * WA + sx) * OO);
        bf16x8 v = __builtin_bit_cast(bf16x8, u);
        const float* wp = upwt + wi * OO + c0;
#pragma unroll
        for (int j = 0; j < 8; j++) acc[j] += (float)v[j] * wp[j];
    };
    if (y0v && x0v) tap(sy0, sx0, iy0 * 4 + ix0);
    if (y0v && x1v) tap(sy0, sx1, iy0 * 4 + ix1);
    if (y1v && x0v) tap(sy1, sx0, iy1 * 4 + ix0);
    if (y1v && x1v) tap(sy1, sx1, iy1 * 4 + ix1);

    bf16x8 r;
#pragma unroll
    for (int j = 0; j < 8; j++) r[j] = (__bf16)acc[j];
    *reinterpret_cast<bf16x8*>(zcl + (((size_t)b * HC + y) * WC + x) * OO + c0) = r;
}

// ---------------- launch ----------------
extern "C" void kernel_launch(void* const* d_in, const int* in_sizes, int n_in,
                              void* d_out, int out_size, void* d_ws, size_t ws_size,
                              hipStream_t stream) {
    (void)in_sizes; (void)n_in; (void)out_size; (void)ws_size;
    const float* x      = (const float*)d_in[0];
    const float* pre_x  = (const float*)d_in[1];
    const float* pwom   = (const float*)d_in[2];
    const float* pbom   = (const float*)d_in[3];
    const float* pw     = (const float*)d_in[4];
    const float* pb     = (const float*)d_in[5];
    const float* pgam   = (const float*)d_in[6];
    const float* pbet   = (const float*)d_in[7];
    const float* pmea   = (const float*)d_in[8];
    const float* pvar   = (const float*)d_in[9];
    const float* nwom   = (const float*)d_in[10];
    const float* nbom   = (const float*)d_in[11];
    const float* nw     = (const float*)d_in[12];
    const float* nb     = (const float*)d_in[13];
    const float* ngam   = (const float*)d_in[14];
    const float* nbet   = (const float*)d_in[15];
    const float* nmea   = (const float*)d_in[16];
    const float* nvar   = (const float*)d_in[17];
    const float* upw    = (const float*)d_in[18];
    float* out = (float*)d_out;

    char* wsb = (char*)d_ws;
    __bf16* xclA  = (__bf16*)(wsb + 0);          //  8,388,608 B
    __bf16* h1cl  = (__bf16*)(wsb + 8388608);    //  4,194,304
    __bf16* zcl   = (__bf16*)(wsb + 12582912);   // 16,777,216
    float*  omA   = (float*) (wsb + 29360128);   //  2,097,152
    float*  omC   = (float*) (wsb + 31457280);   //  8,388,608
    __bf16* wkAp  = (__bf16*)(wsb + 39845888);   //    589,824
    __bf16* wkCp  = (__bf16*)(wsb + 40435712);   //    294,912
    __bf16* womAp = (__bf16*)(wsb + 40730624);   //    147,456
    __bf16* womCp = (__bf16*)(wsb + 40878080);   //     73,728
    float*  upwt  = (float*) (wsb + 40951808);   //      8,192
    float*  scA   = (float*) (wsb + 40960000);
    float*  shA   = (float*) (wsb + 40960512);
    float*  scC   = (float*) (wsb + 40961024);
    float*  shC   = (float*) (wsb + 40961536);   // end ~41.0 MB

    // prepacks
    pack_w_kernel<<<1152, 256, 0, stream>>>(pw, wkAp, CA, 8, 128);
    pack_w_kernel<<<576, 256, 0, stream>>>(nw, wkCp, CC, 8, 128);
    pack_w_kernel<<<288, 256, 0, stream>>>(pwom, womAp, CA, 2, 27);
    pack_w_kernel<<<144, 256, 0, stream>>>(nwom, womCp, CC, 2, 27);
    bn_prepack_kernel<<<1, 128, 0, stream>>>(pgam, pbet, pmea, pvar, pb, scA, shA);
    bn_prepack_kernel<<<1, 128, 0, stream>>>(ngam, nbet, nmea, nvar, nb, scC, shC);
    pack_upw_kernel<<<8, 256, 0, stream>>>(upw, upwt);
    to_cl_kernel<CA, HA*WA><<<BN2 * (CA/32) * (HA*WA/64), 256, 0, stream>>>(x, xclA);

    // stage A
    om_mfma_kernel<CA, HA, WA><<<BN2 * HA * (WA/64), 256, 0, stream>>>(xclA, womAp, pbom, omA);
    dcn_mfma2_kernel<CA, HA, WA, false><<<BN2 * HA * (WA/64), 256, 0, stream>>>(
        xclA, omA, wkAp, scA, shA, nullptr, h1cl);

    // upsample + residual
    upsample_cl_kernel<<<(BN2 * 16 * HC * WC) / 256, 256, 0, stream>>>(h1cl, pre_x, upwt, zcl);

    // stage C
    om_mfma_kernel<CC, HC, WC><<<BN2 * HC * (WC/64), 256, 0, stream>>>(zcl, womCp, nbom, omC);
    dcn_mfma2_kernel<CC, HC, WC, true><<<BN2 * HC * (WC/64), 256, 0, stream>>>(
        zcl, omC, wkCp, scC, shC, out, nullptr);
}

// Round 8
// 282.968 us; speedup vs baseline: 5.8633x; 1.0803x over previous
//
#include <hip/hip_runtime.h>
#include <hip/hip_bf16.h>
#include <math.h>

typedef __bf16 bf16x8 __attribute__((ext_vector_type(8)));
typedef float  f32x4  __attribute__((ext_vector_type(4)));

static constexpr int BN2 = 2;
static constexpr int CA = 256, HA = 64, WA = 128;   // stage A input
static constexpr int OO = 128;                      // output channels
static constexpr int HC = 128, WC = 256, CC = 128;  // stage C

// ---------- pack weights into MFMA B-fragment layout: [9][C/32][OT][64][8] bf16 ----------
__global__ void pack_w_kernel(const float* __restrict__ w, __bf16* __restrict__ out,
                              int Cin, int OT, int Oreal) {
    int NCH = Cin / 32;
    int idx = blockIdx.x * blockDim.x + threadIdx.x;
    int total = 9 * NCH * OT * 512;
    if (idx >= total) return;
    int j    = idx & 7;
    int lane = (idx >> 3) & 63;
    int ot   = (idx >> 9) % OT;
    int rest = (idx >> 9) / OT;
    int ch = rest % NCH;
    int k  = rest / NCH;
    int o = ot * 16 + (lane & 15);
    int c = ch * 32 + (lane >> 4) * 8 + j;
    float v = (o < Oreal) ? w[((size_t)o * Cin + c) * 9 + k] : 0.f;
    out[idx] = (__bf16)v;
}

// ---------- NCHW fp32 -> NHWC bf16 (LDS tile transpose) ----------
template<int C, int HW>
__global__ __launch_bounds__(256) void to_cl_kernel(const float* __restrict__ x,
                                                    __bf16* __restrict__ xcl) {
    constexpr int NCB = C / 32;
    constexpr int NPB = HW / 64;
    int blk = blockIdx.x;
    int pblk = blk % NPB;
    int cblk = (blk / NPB) % NCB;
    int b = blk / (NPB * NCB);
    int t = threadIdx.x;
    __shared__ float st[32][65];
    int r = t >> 6, q = t & 63;
#pragma unroll
    for (int i = 0; i < 8; i++) {
        int c = cblk * 32 + i * 4 + r;
        st[i * 4 + r][q] = x[((size_t)b * C + c) * HW + pblk * 64 + q];
    }
    __syncthreads();
    int p = t >> 2, cq = t & 3;
    bf16x8 v;
#pragma unroll
    for (int j = 0; j < 8; j++) v[j] = (__bf16)st[cq * 8 + j][p];
    *reinterpret_cast<bf16x8*>(xcl + ((size_t)b * HW + pblk * 64 + p) * C + cblk * 32 + cq * 8) = v;
}

// ---------- fold bias+BN into per-o scale/shift ----------
__global__ void bn_prepack_kernel(const float* __restrict__ g,  const float* __restrict__ be,
                                  const float* __restrict__ mu, const float* __restrict__ va,
                                  const float* __restrict__ bi,
                                  float* __restrict__ sc, float* __restrict__ sh) {
    int i = blockIdx.x * blockDim.x + threadIdx.x;
    if (i >= OO) return;
    float s = g[i] * rsqrtf(va[i] + 1e-5f);
    sc[i] = s;
    sh[i] = (bi[i] - mu[i]) * s + be[i];
}

// ---------- upw[O][4][4] -> upwt[16][O] ----------
__global__ void pack_upw_kernel(const float* __restrict__ upw, float* __restrict__ upwt) {
    int idx = blockIdx.x * blockDim.x + threadIdx.x;
    if (idx >= 16 * OO) return;
    int i = idx >> 7;
    int o = idx & 127;
    upwt[i * OO + o] = upw[o * 16 + i];
}

// ---------- om-conv as MFMA with window staging (r7-proven) ----------
template<int C, int H, int W>
__global__ __launch_bounds__(256) void om_mfma_kernel(
    const __bf16* __restrict__ xcl,   // [B][H][W][C]
    const __bf16* __restrict__ womp,  // [9][C/32][2][64][8] bf16
    const float* __restrict__ bom,    // [27]
    float* __restrict__ omcl)         // [B][H][W][32]
{
    constexpr int NCH = C / 32;
    constexpr int WS = 201;
    const int nwt = W / 64;
    int wt = blockIdx.x % nwt;
    int h  = (blockIdx.x / nwt) % H;
    int b  = blockIdx.x / (nwt * H);
    int t = threadIdx.x;
    int wave = t >> 6, lane = t & 63;
    int row = lane & 15, kg = lane >> 4;

    __shared__ float win[32 * WS];

    f32x4 acc0 = {0.f, 0.f, 0.f, 0.f};
    f32x4 acc1 = {0.f, 0.f, 0.f, 0.f};
    const __bf16* xb = xcl + (size_t)b * H * W * C;

    for (int ch = 0; ch < NCH; ch++) {
        for (int i = 0; i < 4; i++) {
            int idx = i * 256 + t;
            if (idx < 792) {
                int cq  = idx & 3;
                int pix = idx >> 2;
                int ry = pix / 66, rx = pix % 66;
                int y = h + ry - 1, xx = wt * 64 + rx - 1;
                bool valid = (y >= 0) && (y < H) && (xx >= 0) && (xx < W);
                int yc = min(max(y, 0), H - 1), xc = min(max(xx, 0), W - 1);
                uint4 u = *reinterpret_cast<const uint4*>(
                    xb + ((size_t)yc * W + xc) * C + ch * 32 + cq * 8);
                if (!valid) { u.x = 0; u.y = 0; u.z = 0; u.w = 0; }
                bf16x8 v = __builtin_bit_cast(bf16x8, u);
#pragma unroll
                for (int j = 0; j < 8; j++)
                    win[(cq * 8 + j) * WS + pix] = (float)v[j];
            }
        }
        __syncthreads();
#pragma unroll
        for (int k = 0; k < 9; k++) {
            int off = (k / 3) * 66 + (k % 3) + wave * 16 + row;
            bf16x8 a;
#pragma unroll
            for (int j = 0; j < 8; j++)
                a[j] = (__bf16)win[(kg * 8 + j) * WS + off];
            const __bf16* wbc = womp + ((size_t)k * NCH + ch) * 1024 + lane * 8;
            bf16x8 b0 = *reinterpret_cast<const bf16x8*>(wbc);
            bf16x8 b1 = *reinterpret_cast<const bf16x8*>(wbc + 512);
            acc0 = __builtin_amdgcn_mfma_f32_16x16x32_bf16(a, b0, acc0, 0, 0, 0);
            acc1 = __builtin_amdgcn_mfma_f32_16x16x32_bf16(a, b1, acc1, 0, 0, 0);
        }
        __syncthreads();
    }

    float* ob = omcl + (((size_t)b * H + h) * W + wt * 64 + wave * 16 + kg * 4) * 32;
    float bb0 = bom[row];
#pragma unroll
    for (int j = 0; j < 4; j++)
        ob[(size_t)j * 32 + row] = acc0[j] + bb0;
    if (row < 11) {
        float bb1 = bom[16 + row];
#pragma unroll
        for (int j = 0; j < 4; j++)
            ob[(size_t)j * 32 + 16 + row] = acc1[j] + bb1;
    }
}

// ---------- DCN: pipelined double-buffered bf16 staging + MFMA ----------
template<int C, int H, int W, bool CF_OUT>
__global__ __launch_bounds__(256) void dcn_mfma3_kernel(
    const __bf16* __restrict__ xcl,  // [B][H][W][C]
    const float* __restrict__ omcl,  // [B][H][W][32]
    const __bf16* __restrict__ wkp,  // [9][C/32][8][64][8] bf16 (pack_w)
    const float* __restrict__ sc, const float* __restrict__ sh,
    float* __restrict__ outcf,       // CF_OUT: [B][O][H][W] fp32
    __bf16* __restrict__ outcl)      // else:   [B][H][W][O] bf16
{
    constexpr int NCH = C / 32;
    constexpr int NS  = 9 * NCH;
    const int nwt = W / 64;
    int wt = blockIdx.x % nwt;
    int h  = (blockIdx.x / nwt) % H;
    int b  = blockIdx.x / (nwt * H);
    int t = threadIdx.x;
    int wave = t >> 6, lane = t & 63;
    int row = lane & 15, kg = lane >> 4;

    __shared__ __align__(16) char smem[33536];
    int4*   pki  = reinterpret_cast<int4*>(smem);                 // [576]
    float4* pkw  = reinterpret_cast<float4*>(smem + 9216);        // [576]
    __bf16* sbuf = reinterpret_cast<__bf16*>(smem + 18432);       // [2][64][32] swizzled
    float*  tr   = reinterpret_cast<float*>(smem);                // tr[128][65] (post-loop alias)

    // per-(pos,k) precompute (proven r5)
    const float* omb = omcl + (((size_t)b * H + h) * W + wt * 64) * 32;
    for (int idx = t; idx < 576; idx += 256) {
        int p = idx & 63;
        int k = idx >> 6;
        float o1 = omb[p * 32 + k];
        float o2 = omb[p * 32 + 9 + k];
        float mm = omb[p * 32 + 18 + k];
        mm = 1.f / (1.f + expf(-mm));
        float py = o1 + (float)(h + k / 3 - 1);
        float px = o2 + (float)(wt * 64 + p + k % 3 - 1);
        float y0f = floorf(py), x0f = floorf(px);
        float wy = py - y0f, wx = px - x0f;
        int y0 = (int)y0f, x0 = (int)x0f;
        bool y0v = (y0 >= 0) && (y0 < H);
        bool y1v = (y0 + 1 >= 0) && (y0 + 1 < H);
        bool x0v = (x0 >= 0) && (x0 < W);
        bool x1v = (x0 + 1 >= 0) && (x0 + 1 < W);
        int y0c = min(max(y0, 0), H - 1) * W;
        int y1c = min(max(y0 + 1, 0), H - 1) * W;
        int x0c = min(max(x0, 0), W - 1);
        int x1c = min(max(x0 + 1, 0), W - 1);
        int4 pi;
        pi.x = (y0c + x0c) * C; pi.y = (y0c + x1c) * C;
        pi.z = (y1c + x0c) * C; pi.w = (y1c + x1c) * C;
        float4 pw;
        pw.x = (y0v && x0v) ? (1.f - wy) * (1.f - wx) * mm : 0.f;
        pw.y = (y0v && x1v) ? (1.f - wy) * wx * mm : 0.f;
        pw.z = (y1v && x0v) ? wy * (1.f - wx) * mm : 0.f;
        pw.w = (y1v && x1v) ? wy * wx * mm : 0.f;
        pki[idx] = pi;
        pkw[idx] = pw;
    }
    __syncthreads();

    f32x4 acc[8];
#pragma unroll
    for (int i = 0; i < 8; i++) acc[i] = {0.f, 0.f, 0.f, 0.f};

    const __bf16* xb = xcl + (size_t)b * H * W * C;
    int pc = t & 63;   // phase-1 gather position
    int cq = t >> 6;   // phase-1 channel octet (wave-uniform)

    // XOR-swizzled 16B-unit addresses: u = unit ^ ((row>>1)&3), same involution
    // on write (row=pc, unit=cq) and read (row=wave*16+row, unit=kg).  [rule #21]
    __bf16* wp0 = sbuf + pc * 32 + ((cq ^ ((pc >> 1) & 3)) << 3);
    int rrow = wave * 16 + row;
    const __bf16* rp0 = sbuf + rrow * 32 + ((kg ^ ((rrow >> 1) & 3)) << 3);

    uint4 u00, u01, u10, u11;
    float4 pwc;
    auto LOAD = [&](int s) {
        int k = s / NCH, ch = s - k * NCH;
        int4 pi = pki[k * 64 + pc];
        pwc = pkw[k * 64 + pc];
        int cb = ch * 32 + cq * 8;
        u00 = *reinterpret_cast<const uint4*>(xb + pi.x + cb);
        u01 = *reinterpret_cast<const uint4*>(xb + pi.y + cb);
        u10 = *reinterpret_cast<const uint4*>(xb + pi.z + cb);
        u11 = *reinterpret_cast<const uint4*>(xb + pi.w + cb);
    };

    LOAD(0);
    int buf = 0;
    // One barrier per step is safe: write(s) targets the buffer last read at
    // s-2; every wave's read(s-2) precedes its barrier(s-1), and write(s)
    // happens only after passing barrier(s-1).
    for (int s = 0; s < NS; s++) {
        {   // BLEND(s): vmcnt wait + fp32 bilinear blend + cvt, store bf16x8
            bf16x8 v00 = __builtin_bit_cast(bf16x8, u00);
            bf16x8 v01 = __builtin_bit_cast(bf16x8, u01);
            bf16x8 v10 = __builtin_bit_cast(bf16x8, u10);
            bf16x8 v11 = __builtin_bit_cast(bf16x8, u11);
            bf16x8 rg;
#pragma unroll
            for (int j = 0; j < 8; j++) {
                float sv = pwc.x * (float)v00[j] + pwc.y * (float)v01[j]
                         + pwc.z * (float)v10[j] + pwc.w * (float)v11[j];
                rg[j] = (__bf16)sv;
            }
            *reinterpret_cast<bf16x8*>(wp0 + buf * 2048) = rg;
        }
        if (s + 1 < NS) LOAD(s + 1);   // issue next loads; drain under MFMA
        __syncthreads();
        {   // phase 2: one ds_read_b128 A-frag + 8 MFMA
            bf16x8 a = *reinterpret_cast<const bf16x8*>(rp0 + buf * 2048);
            const __bf16* wbc = wkp + (size_t)s * 4096 + lane * 8;
#pragma unroll
            for (int ot = 0; ot < 8; ot++) {
                bf16x8 bv = *reinterpret_cast<const bf16x8*>(wbc + ot * 512);
                acc[ot] = __builtin_amdgcn_mfma_f32_16x16x32_bf16(a, bv, acc[ot], 0, 0, 0);
            }
        }
        buf ^= 1;
    }

    // epilogue with MFMA D mapping: col = lane&15 -> o, row = kg*4+j -> pos
    if (CF_OUT) {
        __syncthreads();   // all phase-2 reads done before tr aliases smem
#pragma unroll
        for (int ot = 0; ot < 8; ot++) {
            int o = ot * 16 + row;
            float s = sc[o], hh = sh[o];
            int p = wave * 16 + kg * 4;
#pragma unroll
            for (int j = 0; j < 4; j++) {
                tr[o * 65 + p + j] = fmaxf(acc[ot][j] * s + hh, 0.f);
            }
        }
        __syncthreads();
        float* ob = outcf + (size_t)b * OO * H * W + (size_t)h * W + wt * 64;
        for (int i = 0; i < 32; i++) {
            int ii = i * 256 + t;
            int o = ii >> 6, p = ii & 63;
            ob[(size_t)o * H * W + p] = tr[o * 65 + p];
        }
    } else {
        __bf16* ob = outcl + (((size_t)b * H + h) * W + wt * 64) * OO;
        int p0 = wave * 16 + kg * 4;
#pragma unroll
        for (int ot = 0; ot < 8; ot++) {
            int o = ot * 16 + row;
            float s = sc[o], hh = sh[o];
#pragma unroll
            for (int j = 0; j < 4; j++) {
                float y = fmaxf(acc[ot][j] * s + hh, 0.f);
                ob[(size_t)(p0 + j) * OO + o] = (__bf16)y;
            }
        }
    }
}

// ---------- bilinear x2 depthwise transposed conv + residual ----------
__global__ __launch_bounds__(256) void upsample_cl_kernel(
    const __bf16* __restrict__ h1cl,  // [B][HA][WA][O] bf16
    const float* __restrict__ prex,   // [B][O][HC][WC] fp32
    const float* __restrict__ upwt,   // [16][O]
    __bf16* __restrict__ zcl)         // [B][HC][WC][O] bf16
{
    int idx = blockIdx.x * blockDim.x + threadIdx.x;
    int x  = idx & (WC - 1);
    int y  = (idx >> 8) & (HC - 1);
    int cg = (idx >> 15) & 15;
    int b  = idx >> 19;

    int sy0, iy0, sy1, iy1, sx0, ix0, sx1, ix1;
    if (y & 1) { sy0 = (y - 1) >> 1; iy0 = 2; sy1 = sy0 + 1; iy1 = 0; }
    else       { sy0 = (y >> 1) - 1; iy0 = 3; sy1 = sy0 + 1; iy1 = 1; }
    if (x & 1) { sx0 = (x - 1) >> 1; ix0 = 2; sx1 = sx0 + 1; ix1 = 0; }
    else       { sx0 = (x >> 1) - 1; ix0 = 3; sx1 = sx0 + 1; ix1 = 1; }

    int c0 = cg * 8;
    float acc[8];
    const float* pp = prex + ((size_t)b * OO + c0) * (HC * WC) + (size_t)y * WC + x;
#pragma unroll
    for (int j = 0; j < 8; j++) acc[j] = pp[(size_t)j * HC * WC];

    bool y0v = sy0 >= 0, y1v = sy1 < HA;
    bool x0v = sx0 >= 0, x1v = sx1 < WA;
    const __bf16* hb = h1cl + (size_t)b * HA * WA * OO + c0;

    auto tap = [&](int sy, int sx, int wi) {
        uint4 u = *reinterpret_cast<const uint4*>(hb + ((size_t)sy * WA + sx) * OO);
        bf16x8 v = __builtin_bit_cast(bf16x8, u);
        const float* wp = upwt + wi * OO + c0;
#pragma unroll
        for (int j = 0; j < 8; j++) acc[j] += (float)v[j] * wp[j];
    };
    if (y0v && x0v) tap(sy0, sx0, iy0 * 4 + ix0);
    if (y0v && x1v) tap(sy0, sx1, iy0 * 4 + ix1);
    if (y1v && x0v) tap(sy1, sx0, iy1 * 4 + ix0);
    if (y1v && x1v) tap(sy1, sx1, iy1 * 4 + ix1);

    bf16x8 r;
#pragma unroll
    for (int j = 0; j < 8; j++) r[j] = (__bf16)acc[j];
    *reinterpret_cast<bf16x8*>(zcl + (((size_t)b * HC + y) * WC + x) * OO + c0) = r;
}

// ---------------- launch ----------------
extern "C" void kernel_launch(void* const* d_in, const int* in_sizes, int n_in,
                              void* d_out, int out_size, void* d_ws, size_t ws_size,
                              hipStream_t stream) {
    (void)in_sizes; (void)n_in; (void)out_size; (void)ws_size;
    const float* x      = (const float*)d_in[0];
    const float* pre_x  = (const float*)d_in[1];
    const float* pwom   = (const float*)d_in[2];
    const float* pbom   = (const float*)d_in[3];
    const float* pw     = (const float*)d_in[4];
    const float* pb     = (const float*)d_in[5];
    const float* pgam   = (const float*)d_in[6];
    const float* pbet   = (const float*)d_in[7];
    const float* pmea   = (const float*)d_in[8];
    const float* pvar   = (const float*)d_in[9];
    const float* nwom   = (const float*)d_in[10];
    const float* nbom   = (const float*)d_in[11];
    const float* nw     = (const float*)d_in[12];
    const float* nb     = (const float*)d_in[13];
    const float* ngam   = (const float*)d_in[14];
    const float* nbet   = (const float*)d_in[15];
    const float* nmea   = (const float*)d_in[16];
    const float* nvar   = (const float*)d_in[17];
    const float* upw    = (const float*)d_in[18];
    float* out = (float*)d_out;

    char* wsb = (char*)d_ws;
    __bf16* xclA  = (__bf16*)(wsb + 0);          //  8,388,608 B
    __bf16* h1cl  = (__bf16*)(wsb + 8388608);    //  4,194,304
    __bf16* zcl   = (__bf16*)(wsb + 12582912);   // 16,777,216
    float*  omA   = (float*) (wsb + 29360128);   //  2,097,152
    float*  omC   = (float*) (wsb + 31457280);   //  8,388,608
    __bf16* wkAp  = (__bf16*)(wsb + 39845888);   //    589,824
    __bf16* wkCp  = (__bf16*)(wsb + 40435712);   //    294,912
    __bf16* womAp = (__bf16*)(wsb + 40730624);   //    147,456
    __bf16* womCp = (__bf16*)(wsb + 40878080);   //     73,728
    float*  upwt  = (float*) (wsb + 40951808);   //      8,192
    float*  scA   = (float*) (wsb + 40960000);
    float*  shA   = (float*) (wsb + 40960512);
    float*  scC   = (float*) (wsb + 40961024);
    float*  shC   = (float*) (wsb + 40961536);   // end ~41.0 MB

    // prepacks
    pack_w_kernel<<<1152, 256, 0, stream>>>(pw, wkAp, CA, 8, 128);
    pack_w_kernel<<<576, 256, 0, stream>>>(nw, wkCp, CC, 8, 128);
    pack_w_kernel<<<288, 256, 0, stream>>>(pwom, womAp, CA, 2, 27);
    pack_w_kernel<<<144, 256, 0, stream>>>(nwom, womCp, CC, 2, 27);
    bn_prepack_kernel<<<1, 128, 0, stream>>>(pgam, pbet, pmea, pvar, pb, scA, shA);
    bn_prepack_kernel<<<1, 128, 0, stream>>>(ngam, nbet, nmea, nvar, nb, scC, shC);
    pack_upw_kernel<<<8, 256, 0, stream>>>(upw, upwt);
    to_cl_kernel<CA, HA*WA><<<BN2 * (CA/32) * (HA*WA/64), 256, 0, stream>>>(x, xclA);

    // stage A
    om_mfma_kernel<CA, HA, WA><<<BN2 * HA * (WA/64), 256, 0, stream>>>(xclA, womAp, pbom, omA);
    dcn_mfma3_kernel<CA, HA, WA, false><<<BN2 * HA * (WA/64), 256, 0, stream>>>(
        xclA, omA, wkAp, scA, shA, nullptr, h1cl);

    // upsample + residual
    upsample_cl_kernel<<<(BN2 * 16 * HC * WC) / 256, 256, 0, stream>>>(h1cl, pre_x, upwt, zcl);

    // stage C
    om_mfma_kernel<CC, HC, WC><<<BN2 * HC * (WC/64), 256, 0, stream>>>(zcl, womCp, nbom, omC);
    dcn_mfma3_kernel<CC, HC, WC, true><<<BN2 * HC * (WC/64), 256, 0, stream>>>(
        zcl, omC, wkCp, scC, shC, out, nullptr);
}

// Round 9
// 193.482 us; speedup vs baseline: 8.5751x; 1.4625x over previous
//
#include <hip/hip_runtime.h>
#include <hip/hip_bf16.h>
#include <math.h>

typedef __bf16 bf16x8 __attribute__((ext_vector_type(8)));
typedef float  f32x4  __attribute__((ext_vector_type(4)));

static constexpr int BN2 = 2;
static constexpr int CA = 256, HA = 64, WA = 128;   // stage A input
static constexpr int OO = 128;                      // output channels
static constexpr int HC = 128, WC = 256, CC = 128;  // stage C

// ---------- pack weights into MFMA B-fragment layout: [9][C/32][OT][64][8] bf16 ----------
__global__ void pack_w_kernel(const float* __restrict__ w, __bf16* __restrict__ out,
                              int Cin, int OT, int Oreal) {
    int NCH = Cin / 32;
    int idx = blockIdx.x * blockDim.x + threadIdx.x;
    int total = 9 * NCH * OT * 512;
    if (idx >= total) return;
    int j    = idx & 7;
    int lane = (idx >> 3) & 63;
    int ot   = (idx >> 9) % OT;
    int rest = (idx >> 9) / OT;
    int ch = rest % NCH;
    int k  = rest / NCH;
    int o = ot * 16 + (lane & 15);
    int c = ch * 32 + (lane >> 4) * 8 + j;
    float v = (o < Oreal) ? w[((size_t)o * Cin + c) * 9 + k] : 0.f;
    out[idx] = (__bf16)v;
}

// ---------- NCHW fp32 -> NHWC bf16 (LDS tile transpose) ----------
template<int C, int HW>
__global__ __launch_bounds__(256) void to_cl_kernel(const float* __restrict__ x,
                                                    __bf16* __restrict__ xcl) {
    constexpr int NCB = C / 32;
    constexpr int NPB = HW / 64;
    int blk = blockIdx.x;
    int pblk = blk % NPB;
    int cblk = (blk / NPB) % NCB;
    int b = blk / (NPB * NCB);
    int t = threadIdx.x;
    __shared__ float st[32][65];
    int r = t >> 6, q = t & 63;
#pragma unroll
    for (int i = 0; i < 8; i++) {
        int c = cblk * 32 + i * 4 + r;
        st[i * 4 + r][q] = x[((size_t)b * C + c) * HW + pblk * 64 + q];
    }
    __syncthreads();
    int p = t >> 2, cq = t & 3;
    bf16x8 v;
#pragma unroll
    for (int j = 0; j < 8; j++) v[j] = (__bf16)st[cq * 8 + j][p];
    *reinterpret_cast<bf16x8*>(xcl + ((size_t)b * HW + pblk * 64 + p) * C + cblk * 32 + cq * 8) = v;
}

// ---------- fold bias+BN into per-o scale/shift ----------
__global__ void bn_prepack_kernel(const float* __restrict__ g,  const float* __restrict__ be,
                                  const float* __restrict__ mu, const float* __restrict__ va,
                                  const float* __restrict__ bi,
                                  float* __restrict__ sc, float* __restrict__ sh) {
    int i = blockIdx.x * blockDim.x + threadIdx.x;
    if (i >= OO) return;
    float s = g[i] * rsqrtf(va[i] + 1e-5f);
    sc[i] = s;
    sh[i] = (bi[i] - mu[i]) * s + be[i];
}

// ---------- upw[O][4][4] -> upwt[16][O] ----------
__global__ void pack_upw_kernel(const float* __restrict__ upw, float* __restrict__ upwt) {
    int idx = blockIdx.x * blockDim.x + threadIdx.x;
    if (idx >= 16 * OO) return;
    int i = idx >> 7;
    int o = idx & 127;
    upwt[i * OO + o] = upw[o * 16 + i];
}

// ---------- om-conv as MFMA with window staging (r7-proven) ----------
template<int C, int H, int W>
__global__ __launch_bounds__(256) void om_mfma_kernel(
    const __bf16* __restrict__ xcl,   // [B][H][W][C]
    const __bf16* __restrict__ womp,  // [9][C/32][2][64][8] bf16
    const float* __restrict__ bom,    // [27]
    float* __restrict__ omcl)         // [B][H][W][32]
{
    constexpr int NCH = C / 32;
    constexpr int WS = 201;
    const int nwt = W / 64;
    int wt = blockIdx.x % nwt;
    int h  = (blockIdx.x / nwt) % H;
    int b  = blockIdx.x / (nwt * H);
    int t = threadIdx.x;
    int wave = t >> 6, lane = t & 63;
    int row = lane & 15, kg = lane >> 4;

    __shared__ float win[32 * WS];

    f32x4 acc0 = {0.f, 0.f, 0.f, 0.f};
    f32x4 acc1 = {0.f, 0.f, 0.f, 0.f};
    const __bf16* xb = xcl + (size_t)b * H * W * C;

    for (int ch = 0; ch < NCH; ch++) {
        for (int i = 0; i < 4; i++) {
            int idx = i * 256 + t;
            if (idx < 792) {
                int cq  = idx & 3;
                int pix = idx >> 2;
                int ry = pix / 66, rx = pix % 66;
                int y = h + ry - 1, xx = wt * 64 + rx - 1;
                bool valid = (y >= 0) && (y < H) && (xx >= 0) && (xx < W);
                int yc = min(max(y, 0), H - 1), xc = min(max(xx, 0), W - 1);
                uint4 u = *reinterpret_cast<const uint4*>(
                    xb + ((size_t)yc * W + xc) * C + ch * 32 + cq * 8);
                if (!valid) { u.x = 0; u.y = 0; u.z = 0; u.w = 0; }
                bf16x8 v = __builtin_bit_cast(bf16x8, u);
#pragma unroll
                for (int j = 0; j < 8; j++)
                    win[(cq * 8 + j) * WS + pix] = (float)v[j];
            }
        }
        __syncthreads();
#pragma unroll
        for (int k = 0; k < 9; k++) {
            int off = (k / 3) * 66 + (k % 3) + wave * 16 + row;
            bf16x8 a;
#pragma unroll
            for (int j = 0; j < 8; j++)
                a[j] = (__bf16)win[(kg * 8 + j) * WS + off];
            const __bf16* wbc = womp + ((size_t)k * NCH + ch) * 1024 + lane * 8;
            bf16x8 b0 = *reinterpret_cast<const bf16x8*>(wbc);
            bf16x8 b1 = *reinterpret_cast<const bf16x8*>(wbc + 512);
            acc0 = __builtin_amdgcn_mfma_f32_16x16x32_bf16(a, b0, acc0, 0, 0, 0);
            acc1 = __builtin_amdgcn_mfma_f32_16x16x32_bf16(a, b1, acc1, 0, 0, 0);
        }
        __syncthreads();
    }

    float* ob = omcl + (((size_t)b * H + h) * W + wt * 64 + wave * 16 + kg * 4) * 32;
    float bb0 = bom[row];
#pragma unroll
    for (int j = 0; j < 4; j++)
        ob[(size_t)j * 32 + row] = acc0[j] + bb0;
    if (row < 11) {
        float bb1 = bom[16 + row];
#pragma unroll
        for (int j = 0; j < 4; j++)
            ob[(size_t)j * 32 + 16 + row] = acc1[j] + bb1;
    }
}

// ---------- DCN v4: wave-autonomous 16-pos tiles, coalesced gather, split-K waves ----------
// lane = pos*4 + cq  (4 lanes share one pixel -> 64B contiguous loads, 4x fewer lines)
// per-wave LDS transpose buffer (stride 40 bf16 -> conflict-free write & read, no barrier:
// per-wave DS pipeline is in-order). KS waves split channel chunks; LDS reduce at end.
template<int C, int H, int W, int KS, bool CF_OUT>
__global__ __launch_bounds__(64 * KS) void dcn_mfma4_kernel(
    const __bf16* __restrict__ xcl,  // [B][H][W][C]
    const float* __restrict__ omcl,  // [B][H][W][32]
    const __bf16* __restrict__ wkp,  // [9][C/32][8][64][8] bf16 (pack_w)
    const float* __restrict__ sc, const float* __restrict__ sh,
    float* __restrict__ outcf,       // CF_OUT: [B][O][H][W] fp32
    __bf16* __restrict__ outcl)      // else:   [B][H][W][O] bf16
{
    constexpr int NCH = C / 32;      // 32-channel chunks
    constexpr int CHW = NCH / KS;    // chunks per wave
    constexpr int NSW = 9 * CHW;     // steps per wave
    constexpr int MAIN = 4608 + KS * 2560;          // pk(4608) + KS * dbuf(2*1280)
    constexpr int RED  = (KS - 1) * 9216;           // reduce slices (alias, post-barrier)
    constexpr int SMEM = MAIN > RED ? MAIN : RED;

    const int nwt = W / 16;
    int wt = blockIdx.x % nwt;
    int h  = (blockIdx.x / nwt) % H;
    int b  = blockIdx.x / (nwt * H);
    int t = threadIdx.x;
    int wave = t >> 6, lane = t & 63;
    int row = lane & 15, kg = lane >> 4;     // phase-2 (MFMA) roles
    int pos16 = lane >> 2, cq = lane & 3;    // phase-1 (gather) roles

    __shared__ __align__(16) char smem[SMEM];
    int4*   pki  = reinterpret_cast<int4*>(smem);            // [144]
    float4* pkw  = reinterpret_cast<float4*>(smem + 2304);   // [144]
    __bf16* sbuf = reinterpret_cast<__bf16*>(smem + 4608);   // [KS][2][16*40]

    // per-(pos,k) precompute (r5-proven math, 16-pos tile)
    const float* omb = omcl + (((size_t)b * H + h) * W + wt * 16) * 32;
    for (int idx = t; idx < 144; idx += 64 * KS) {
        int p = idx & 15;
        int k = idx >> 4;
        float o1 = omb[p * 32 + k];
        float o2 = omb[p * 32 + 9 + k];
        float mm = omb[p * 32 + 18 + k];
        mm = 1.f / (1.f + expf(-mm));
        float py = o1 + (float)(h + k / 3 - 1);
        float px = o2 + (float)(wt * 16 + p + k % 3 - 1);
        float y0f = floorf(py), x0f = floorf(px);
        float wy = py - y0f, wx = px - x0f;
        int y0 = (int)y0f, x0 = (int)x0f;
        bool y0v = (y0 >= 0) && (y0 < H);
        bool y1v = (y0 + 1 >= 0) && (y0 + 1 < H);
        bool x0v = (x0 >= 0) && (x0 < W);
        bool x1v = (x0 + 1 >= 0) && (x0 + 1 < W);
        int y0c = min(max(y0, 0), H - 1) * W;
        int y1c = min(max(y0 + 1, 0), H - 1) * W;
        int x0c = min(max(x0, 0), W - 1);
        int x1c = min(max(x0 + 1, 0), W - 1);
        int4 pi;
        pi.x = (y0c + x0c) * C; pi.y = (y0c + x1c) * C;
        pi.z = (y1c + x0c) * C; pi.w = (y1c + x1c) * C;
        float4 pw;
        pw.x = (y0v && x0v) ? (1.f - wy) * (1.f - wx) * mm : 0.f;
        pw.y = (y0v && x1v) ? (1.f - wy) * wx * mm : 0.f;
        pw.z = (y1v && x0v) ? wy * (1.f - wx) * mm : 0.f;
        pw.w = (y1v && x1v) ? wy * wx * mm : 0.f;
        pki[idx] = pi;
        pkw[idx] = pw;
    }
    __syncthreads();

    f32x4 acc[8];
#pragma unroll
    for (int i = 0; i < 8; i++) acc[i] = {0.f, 0.f, 0.f, 0.f};

    const __bf16* xb = xcl + (size_t)b * H * W * C;
    __bf16* sb = sbuf + wave * 1280;                   // 2 bufs x 640 bf16
    __bf16* wp0 = sb + pos16 * 40 + cq * 8;            // write: stride-5-unit spread
    const __bf16* rp0 = sb + row * 40 + kg * 8;        // read : conflict-free

    uint4 u00, u01, u10, u11;
    float4 pwc;
    int kcur = 0, chcur = 0;
    auto LOAD = [&](int ls) {
        int k = ls / CHW, chl = ls - k * CHW;
        int ch = wave * CHW + chl;
        kcur = k; chcur = ch;
        int4 pi = pki[k * 16 + pos16];
        pwc = pkw[k * 16 + pos16];
        int cb = ch * 32 + cq * 8;
        u00 = *reinterpret_cast<const uint4*>(xb + pi.x + cb);
        u01 = *reinterpret_cast<const uint4*>(xb + pi.y + cb);
        u10 = *reinterpret_cast<const uint4*>(xb + pi.z + cb);
        u11 = *reinterpret_cast<const uint4*>(xb + pi.w + cb);
    };

    LOAD(0);
    int buf = 0;
    for (int ls = 0; ls < NSW; ls++) {
        int sg = kcur * NCH + chcur;                   // global step for B-frags
        {   // BLEND: vmcnt wait + fp32 bilinear blend + cvt -> LDS (this wave only)
            bf16x8 v00 = __builtin_bit_cast(bf16x8, u00);
            bf16x8 v01 = __builtin_bit_cast(bf16x8, u01);
            bf16x8 v10 = __builtin_bit_cast(bf16x8, u10);
            bf16x8 v11 = __builtin_bit_cast(bf16x8, u11);
            bf16x8 rg;
#pragma unroll
            for (int j = 0; j < 8; j++) {
                float sv = pwc.x * (float)v00[j] + pwc.y * (float)v01[j]
                         + pwc.z * (float)v10[j] + pwc.w * (float)v11[j];
                rg[j] = (__bf16)sv;
            }
            *reinterpret_cast<bf16x8*>(wp0 + buf * 640) = rg;
        }
        if (ls + 1 < NSW) LOAD(ls + 1);                // next loads drain under MFMA
        {   // per-wave transpose read + 8 MFMA (in-order DS pipe, no barrier)
            bf16x8 a = *reinterpret_cast<const bf16x8*>(rp0 + buf * 640);
            const __bf16* wbc = wkp + (size_t)sg * 4096 + lane * 8;
#pragma unroll
            for (int ot = 0; ot < 8; ot++) {
                bf16x8 bv = *reinterpret_cast<const bf16x8*>(wbc + ot * 512);
                acc[ot] = __builtin_amdgcn_mfma_f32_16x16x32_bf16(a, bv, acc[ot], 0, 0, 0);
            }
        }
        buf ^= 1;
    }

    // split-K reduce: waves 1..KS-1 park partials in LDS (alias, post-barrier), wave 0 sums
    __syncthreads();
    if (wave > 0) {
        float* rd = reinterpret_cast<float*>(smem) + (wave - 1) * 2304;  // 9216B slice
#pragma unroll
        for (int ot = 0; ot < 8; ot++)
            *reinterpret_cast<f32x4*>(rd + lane * 36 + ot * 4) = acc[ot];
    }
    __syncthreads();
    if (wave == 0) {
        for (int s = 0; s < KS - 1; s++) {
            float* rd = reinterpret_cast<float*>(smem) + s * 2304;
#pragma unroll
            for (int ot = 0; ot < 8; ot++) {
                f32x4 v = *reinterpret_cast<const f32x4*>(rd + lane * 36 + ot * 4);
                acc[ot] += v;
            }
        }
        // epilogue, D map: o = ot*16 + row, pos = kg*4 + j
        if (CF_OUT) {
            float* ob = outcf + (size_t)b * OO * H * W + (size_t)h * W + wt * 16;
#pragma unroll
            for (int ot = 0; ot < 8; ot++) {
                int o = ot * 16 + row;
                float s = sc[o], hh = sh[o];
#pragma unroll
                for (int j = 0; j < 4; j++) {
                    float y = fmaxf(acc[ot][j] * s + hh, 0.f);
                    ob[(size_t)o * H * W + kg * 4 + j] = y;
                }
            }
        } else {
            __bf16* ob = outcl + (((size_t)b * H + h) * W + wt * 16) * OO;
#pragma unroll
            for (int ot = 0; ot < 8; ot++) {
                int o = ot * 16 + row;
                float s = sc[o], hh = sh[o];
#pragma unroll
                for (int j = 0; j < 4; j++) {
                    float y = fmaxf(acc[ot][j] * s + hh, 0.f);
                    ob[(size_t)(kg * 4 + j) * OO + o] = (__bf16)y;
                }
            }
        }
    }
}

// ---------- bilinear x2 depthwise transposed conv + residual ----------
__global__ __launch_bounds__(256) void upsample_cl_kernel(
    const __bf16* __restrict__ h1cl,  // [B][HA][WA][O] bf16
    const float* __restrict__ prex,   // [B][O][HC][WC] fp32
    const float* __restrict__ upwt,   // [16][O]
    __bf16* __restrict__ zcl)         // [B][HC][WC][O] bf16
{
    int idx = blockIdx.x * blockDim.x + threadIdx.x;
    int x  = idx & (WC - 1);
    int y  = (idx >> 8) & (HC - 1);
    int cg = (idx >> 15) & 15;
    int b  = idx >> 19;

    int sy0, iy0, sy1, iy1, sx0, ix0, sx1, ix1;
    if (y & 1) { sy0 = (y - 1) >> 1; iy0 = 2; sy1 = sy0 + 1; iy1 = 0; }
    else       { sy0 = (y >> 1) - 1; iy0 = 3; sy1 = sy0 + 1; iy1 = 1; }
    if (x & 1) { sx0 = (x - 1) >> 1; ix0 = 2; sx1 = sx0 + 1; ix1 = 0; }
    else       { sx0 = (x >> 1) - 1; ix0 = 3; sx1 = sx0 + 1; ix1 = 1; }

    int c0 = cg * 8;
    float acc[8];
    const float* pp = prex + ((size_t)b * OO + c0) * (HC * WC) + (size_t)y * WC + x;
#pragma unroll
    for (int j = 0; j < 8; j++) acc[j] = pp[(size_t)j * HC * WC];

    bool y0v = sy0 >= 0, y1v = sy1 < HA;
    bool x0v = sx0 >= 0, x1v = sx1 < WA;
    const __bf16* hb = h1cl + (size_t)b * HA * WA * OO + c0;

    auto tap = [&](int sy, int sx, int wi) {
        uint4 u = *reinterpret_cast<const uint4*>(hb + ((size_t)sy * WA + sx) * OO);
        bf16x8 v = __builtin_bit_cast(bf16x8, u);
        const float* wp = upwt + wi * OO + c0;
#pragma unroll
        for (int j = 0; j < 8; j++) acc[j] += (float)v[j] * wp[j];
    };
    if (y0v && x0v) tap(sy0, sx0, iy0 * 4 + ix0);
    if (y0v && x1v) tap(sy0, sx1, iy0 * 4 + ix1);
    if (y1v && x0v) tap(sy1, sx0, iy1 * 4 + ix0);
    if (y1v && x1v) tap(sy1, sx1, iy1 * 4 + ix1);

    bf16x8 r;
#pragma unroll
    for (int j = 0; j < 8; j++) r[j] = (__bf16)acc[j];
    *reinterpret_cast<bf16x8*>(zcl + (((size_t)b * HC + y) * WC + x) * OO + c0) = r;
}

// ---------------- launch ----------------
extern "C" void kernel_launch(void* const* d_in, const int* in_sizes, int n_in,
                              void* d_out, int out_size, void* d_ws, size_t ws_size,
                              hipStream_t stream) {
    (void)in_sizes; (void)n_in; (void)out_size; (void)ws_size;
    const float* x      = (const float*)d_in[0];
    const float* pre_x  = (const float*)d_in[1];
    const float* pwom   = (const float*)d_in[2];
    const float* pbom   = (const float*)d_in[3];
    const float* pw     = (const float*)d_in[4];
    const float* pb     = (const float*)d_in[5];
    const float* pgam   = (const float*)d_in[6];
    const float* pbet   = (const float*)d_in[7];
    const float* pmea   = (const float*)d_in[8];
    const float* pvar   = (const float*)d_in[9];
    const float* nwom   = (const float*)d_in[10];
    const float* nbom   = (const float*)d_in[11];
    const float* nw     = (const float*)d_in[12];
    const float* nb     = (const float*)d_in[13];
    const float* ngam   = (const float*)d_in[14];
    const float* nbet   = (const float*)d_in[15];
    const float* nmea   = (const float*)d_in[16];
    const float* nvar   = (const float*)d_in[17];
    const float* upw    = (const float*)d_in[18];
    float* out = (float*)d_out;

    char* wsb = (char*)d_ws;
    __bf16* xclA  = (__bf16*)(wsb + 0);          //  8,388,608 B
    __bf16* h1cl  = (__bf16*)(wsb + 8388608);    //  4,194,304
    __bf16* zcl   = (__bf16*)(wsb + 12582912);   // 16,777,216
    float*  omA   = (float*) (wsb + 29360128);   //  2,097,152
    float*  omC   = (float*) (wsb + 31457280);   //  8,388,608
    __bf16* wkAp  = (__bf16*)(wsb + 39845888);   //    589,824
    __bf16* wkCp  = (__bf16*)(wsb + 40435712);   //    294,912
    __bf16* womAp = (__bf16*)(wsb + 40730624);   //    147,456
    __bf16* womCp = (__bf16*)(wsb + 40878080);   //     73,728
    float*  upwt  = (float*) (wsb + 40951808);   //      8,192
    float*  scA   = (float*) (wsb + 40960000);
    float*  shA   = (float*) (wsb + 40960512);
    float*  scC   = (float*) (wsb + 40961024);
    float*  shC   = (float*) (wsb + 40961536);   // end ~41.0 MB

    // prepacks
    pack_w_kernel<<<1152, 256, 0, stream>>>(pw, wkAp, CA, 8, 128);
    pack_w_kernel<<<576, 256, 0, stream>>>(nw, wkCp, CC, 8, 128);
    pack_w_kernel<<<288, 256, 0, stream>>>(pwom, womAp, CA, 2, 27);
    pack_w_kernel<<<144, 256, 0, stream>>>(nwom, womCp, CC, 2, 27);
    bn_prepack_kernel<<<1, 128, 0, stream>>>(pgam, pbet, pmea, pvar, pb, scA, shA);
    bn_prepack_kernel<<<1, 128, 0, stream>>>(ngam, nbet, nmea, nvar, nb, scC, shC);
    pack_upw_kernel<<<8, 256, 0, stream>>>(upw, upwt);
    to_cl_kernel<CA, HA*WA><<<BN2 * (CA/32) * (HA*WA/64), 256, 0, stream>>>(x, xclA);

    // stage A
    om_mfma_kernel<CA, HA, WA><<<BN2 * HA * (WA/64), 256, 0, stream>>>(xclA, womAp, pbom, omA);
    dcn_mfma4_kernel<CA, HA, WA, 4, false><<<BN2 * HA * (WA/16), 256, 0, stream>>>(
        xclA, omA, wkAp, scA, shA, nullptr, h1cl);

    // upsample + residual
    upsample_cl_kernel<<<(BN2 * 16 * HC * WC) / 256, 256, 0, stream>>>(h1cl, pre_x, upwt, zcl);

    // stage C
    om_mfma_kernel<CC, HC, WC><<<BN2 * HC * (WC/64), 256, 0, stream>>>(zcl, womCp, nbom, omC);
    dcn_mfma4_kernel<CC, HC, WC, 2, true><<<BN2 * HC * (WC/16), 128, 0, stream>>>(
        zcl, omC, wkCp, scC, shC, out, nullptr);
}